// Round 1
// baseline (439.117 us; speedup 1.0000x reference)
//
#include <hip/hip_runtime.h>
#include <math.h>

// Problem constants (B=8, C=128, H=W=64, G=2, gc=64, nH=4, dh=32, Hk=Wk=16, n=256)
#define HW 4096
#define NCH 128

// ---------------------------------------------------------------------------
// K1/K5: 1x1 conv (C=128 -> 128 GEMM over 4096 positions per batch)
// grid (16 p-tiles, 8 b, 4 o-chunks), 256 threads; 32 outputs per thread.
// Weights read via wave-uniform indices -> scalar cache loads (dwordx4).
// ---------------------------------------------------------------------------
__global__ __launch_bounds__(256) void conv1x1_kernel(
    const float* __restrict__ x, const float* __restrict__ w,
    float* __restrict__ out) {
  int tid = threadIdx.x;
  int p = blockIdx.x * 256 + tid;
  int b = blockIdx.y;
  int o0 = blockIdx.z * 32;
  const float* xp = x + (size_t)b * NCH * HW + p;
  float acc[32];
#pragma unroll
  for (int j = 0; j < 32; ++j) acc[j] = 0.f;
  for (int i = 0; i < NCH; i += 4) {
    float x0 = xp[(size_t)(i + 0) * HW];
    float x1 = xp[(size_t)(i + 1) * HW];
    float x2 = xp[(size_t)(i + 2) * HW];
    float x3 = xp[(size_t)(i + 3) * HW];
#pragma unroll
    for (int j = 0; j < 32; ++j) {
      const float* wr = w + (o0 + j) * NCH + i;
      acc[j] += wr[0] * x0 + wr[1] * x1 + wr[2] * x2 + wr[3] * x3;
    }
  }
  float* op = out + (size_t)b * NCH * HW + (size_t)o0 * HW + p;
#pragma unroll
  for (int j = 0; j < 32; ++j) op[(size_t)j * HW] = acc[j];
}

// ---------------------------------------------------------------------------
// K2: conv_offset fused: depthwise 5x5 s4 p2 -> BiasFree LN -> GELU -> 1x1(3)
//     -> tanh/sigmoid -> pos (y,x) + dm.  One wave (64 ch) per (bg, p).
// ---------------------------------------------------------------------------
__device__ __forceinline__ float wsum64(float v) {
#pragma unroll
  for (int o = 32; o > 0; o >>= 1) v += __shfl_xor(v, o);
  return v;
}

__global__ __launch_bounds__(64) void conv_offset_kernel(
    const float* __restrict__ q, const float* __restrict__ w_dw,
    const float* __restrict__ ln_w, const float* __restrict__ w_off,
    float* __restrict__ pos, float* __restrict__ dm) {
  int c = threadIdx.x;       // 0..63
  int p = blockIdx.x;        // 0..255
  int bg = blockIdx.y;       // 0..15
  int py = p >> 4, px = p & 15;
  const float* qp = q + (size_t)((bg >> 1) * NCH + (bg & 1) * 64 + c) * HW;
  const float* wd = w_dw + c * 25;
  float acc = 0.f;
#pragma unroll
  for (int ky = 0; ky < 5; ++ky) {
    int iy = 4 * py + ky - 2;
    if (iy < 0 || iy >= 64) continue;
#pragma unroll
    for (int kx = 0; kx < 5; ++kx) {
      int ix = 4 * px + kx - 2;
      if (ix < 0 || ix >= 64) continue;
      acc += wd[ky * 5 + kx] * qp[iy * 64 + ix];
    }
  }
  float mean = wsum64(acc) * (1.f / 64.f);
  float msq = wsum64(acc * acc) * (1.f / 64.f);
  float var = msq - mean * mean;                    // jnp.var (ddof=0)
  float g = acc * rsqrtf(var + 1e-5f) * ln_w[c];    // BiasFree LN
  g = 0.5f * g * (1.f + erff(g * 0.70710678118654752f));  // exact GELU
  float o0 = wsum64(w_off[c] * g);
  float o1 = wsum64(w_off[64 + c] * g);
  float o2 = wsum64(w_off[128 + c] * g);
  if (c == 0) {
    int idx = bg * 256 + p;
    float posy = tanhf(o0) * (1.f / 16.f) + ((py + 0.5f) * (1.f / 8.f) - 1.f);
    float posx = tanhf(o1) * (1.f / 16.f) + ((px + 0.5f) * (1.f / 8.f) - 1.f);
    pos[idx * 2] = posy;
    pos[idx * 2 + 1] = posx;
    dm[idx] = 1.f / (1.f + expf(-o2));
  }
}

// ---------------------------------------------------------------------------
// K3a: xs = grid_sample(x, pos) * dm   (align_corners=True, zeros padding)
// grid (16 bg), 256 threads = sample positions; loop over 64 channels.
// ---------------------------------------------------------------------------
__global__ __launch_bounds__(256) void sample_xs_kernel(
    const float* __restrict__ x, const float* __restrict__ pos,
    const float* __restrict__ dm, float* __restrict__ xs) {
  int p = threadIdx.x;
  int bg = blockIdx.x;
  int idx = bg * 256 + p;
  float posy = pos[idx * 2], posx = pos[idx * 2 + 1];
  float dmv = dm[idx];
  float gx = (posx + 1.f) * 31.5f;   // (g+1)*0.5*(64-1)
  float gy = (posy + 1.f) * 31.5f;
  float x0f = floorf(gx), y0f = floorf(gy);
  int ix = (int)x0f, iy = (int)y0f;
  float fx = gx - x0f, fy = gy - y0f;
  float w00 = (1.f - fx) * (1.f - fy), w10 = fx * (1.f - fy);
  float w01 = (1.f - fx) * fy, w11 = fx * fy;
  bool vx0 = (ix >= 0 && ix < 64), vx1 = (ix + 1 >= 0 && ix + 1 < 64);
  bool vy0 = (iy >= 0 && iy < 64), vy1 = (iy + 1 >= 0 && iy + 1 < 64);
  if (!(vx0 && vy0)) w00 = 0.f;
  if (!(vx1 && vy0)) w10 = 0.f;
  if (!(vx0 && vy1)) w01 = 0.f;
  if (!(vx1 && vy1)) w11 = 0.f;
  int x0c = min(max(ix, 0), 63), x1c = min(max(ix + 1, 0), 63);
  int y0c = min(max(iy, 0), 63), y1c = min(max(iy + 1, 0), 63);
  int i00 = y0c * 64 + x0c, i10 = y0c * 64 + x1c;
  int i01 = y1c * 64 + x0c, i11 = y1c * 64 + x1c;
  int b = bg >> 1;
  int ch0 = (bg & 1) * 64;
  const float* xb = x + ((size_t)b * NCH + ch0) * HW;
  float* xsb = xs + ((size_t)b * NCH + ch0) * 256 + p;
  for (int c = 0; c < 64; ++c) {
    const float* img = xb + (size_t)c * HW;
    float v = w00 * img[i00] + w10 * img[i10] + w01 * img[i01] + w11 * img[i11];
    xsb[(size_t)c * 256] = v * dmv;
  }
}

// ---------------------------------------------------------------------------
// K3b: k = wk*xs, v = wv*xs   grid (16 o-chunks, 8 b, 2 which), 256 thr (=n)
// ---------------------------------------------------------------------------
__global__ __launch_bounds__(256) void kv_kernel(
    const float* __restrict__ xs, const float* __restrict__ wk,
    const float* __restrict__ wv, float* __restrict__ kbuf,
    float* __restrict__ vbuf) {
  int p = threadIdx.x;
  int o0 = blockIdx.x * 8;
  int b = blockIdx.y;
  const float* w = blockIdx.z ? wv : wk;
  float* out = blockIdx.z ? vbuf : kbuf;
  const float* xp = xs + (size_t)b * NCH * 256 + p;
  float acc[8];
#pragma unroll
  for (int j = 0; j < 8; ++j) acc[j] = 0.f;
  for (int i = 0; i < NCH; i += 4) {
    float x0 = xp[(i + 0) * 256], x1 = xp[(i + 1) * 256];
    float x2 = xp[(i + 2) * 256], x3 = xp[(i + 3) * 256];
#pragma unroll
    for (int j = 0; j < 8; ++j) {
      const float* wr = w + (o0 + j) * NCH + i;
      acc[j] += wr[0] * x0 + wr[1] * x1 + wr[2] * x2 + wr[3] * x3;
    }
  }
  float* op = out + ((size_t)b * NCH + o0) * 256 + p;
#pragma unroll
  for (int j = 0; j < 8; ++j) op[j * 256] = acc[j];
}

// ---------------------------------------------------------------------------
// K4: fused attention.  Block = (m-tile of 32 queries, b*4+h). 256 threads.
// Phase A: scores = scale*q.k + bilinear RPE bias (scores in registers).
// Softmax: shfl_xor(32) + LDS cross-wave reduce.  P reuses the k LDS buffer.
// Phase B: out[c][m] = sum_n P[m][n]*v[c][n], v read from global (L2-hot).
// LDS: 256*36 (k / P) + 32*36 (q) + 2*128 (reduce) = ~42.5 KB.
// ---------------------------------------------------------------------------
__global__ __launch_bounds__(256) void attn_kernel(
    const float* __restrict__ q, const float* __restrict__ k,
    const float* __restrict__ v, const float* __restrict__ pos,
    const float* __restrict__ rpe, float* __restrict__ out) {
  __shared__ __align__(16) float s_kp[256 * 36];  // k as [n][36]; later P as [mi][260]
  __shared__ __align__(16) float s_q[32 * 36];    // q tile [m][36]
  __shared__ float s_red[128];
  __shared__ float s_red2[128];

  int tid = threadIdx.x;
  int m0 = blockIdx.x * 32;
  int bh = blockIdx.y;  // b*4 + h
  int b = bh >> 2, h = bh & 3;
  int bg = (b << 1) + (h >> 1);
  const float* kg = k + (size_t)(b * NCH + h * 32) * 256;
  const float* vg = v + (size_t)(b * NCH + h * 32) * 256;
  const float* qg = q + (size_t)(b * NCH + h * 32) * HW + m0;
  const float* rp = rpe + (size_t)h * (127 * 127);
  const float* posg = pos + (size_t)bg * 512;

  // stage k: LDS [n][36] (padded for b128 column reads)
  for (int d = 0; d < 32; ++d) s_kp[tid * 36 + d] = kg[(size_t)d * 256 + tid];
  // stage q tile: LDS [m][36]
  {
    int m = tid & 31;
    int d0 = (tid >> 5) * 4;
#pragma unroll
    for (int dd = 0; dd < 4; ++dd)
      s_q[m * 36 + d0 + dd] = qg[(size_t)(d0 + dd) * HW + m];
  }
  __syncthreads();

  int mi = tid & 31;   // query within tile
  int ng = tid >> 5;   // n-group 0..7 (32 n each)
  int m = m0 + mi;
  float ry = ((m >> 6) + 0.5f) * (1.f / 32.f) - 1.f;
  float rx = ((m & 63) + 0.5f) * (1.f / 32.f) - 1.f;

  float qr[32];
  {
    const float4* qp = (const float4*)&s_q[mi * 36];
#pragma unroll
    for (int t = 0; t < 8; ++t) {
      float4 u = qp[t];
      qr[4 * t] = u.x; qr[4 * t + 1] = u.y; qr[4 * t + 2] = u.z; qr[4 * t + 3] = u.w;
    }
  }

  float sc[32];
#pragma unroll
  for (int i = 0; i < 32; ++i) {
    int n = ng * 32 + i;
    const float4* kp = (const float4*)&s_kp[n * 36];
    float acc = 0.f;
#pragma unroll
    for (int t = 0; t < 8; ++t) {
      float4 u = kp[t];
      acc += qr[4 * t] * u.x + qr[4 * t + 1] * u.y + qr[4 * t + 2] * u.z +
             qr[4 * t + 3] * u.w;
    }
    // RPE bias: bilinear sample of rpe[h] at disp=(qg-pos)*0.5, align_corners
    float py = posg[n * 2], px = posg[n * 2 + 1];
    float gy = ((ry - py) * 0.5f + 1.f) * 63.f;  // (g+1)*0.5*(127-1)
    float gx = ((rx - px) * 0.5f + 1.f) * 63.f;
    float y0f = floorf(gy), x0f = floorf(gx);
    int iy = (int)y0f, ix = (int)x0f;
    float fy = gy - y0f, fx = gx - x0f;
    float w00 = (1.f - fx) * (1.f - fy), w10 = fx * (1.f - fy);
    float w01 = (1.f - fx) * fy, w11 = fx * fy;
    bool vx0 = (unsigned)ix < 127u, vx1 = (unsigned)(ix + 1) < 127u;
    bool vy0 = (unsigned)iy < 127u, vy1 = (unsigned)(iy + 1) < 127u;
    if (!(vx0 && vy0)) w00 = 0.f;
    if (!(vx1 && vy0)) w10 = 0.f;
    if (!(vx0 && vy1)) w01 = 0.f;
    if (!(vx1 && vy1)) w11 = 0.f;
    int x0c = min(max(ix, 0), 126), x1c = min(max(ix + 1, 0), 126);
    int y0c = min(max(iy, 0), 126), y1c = min(max(iy + 1, 0), 126);
    float bias = w00 * rp[y0c * 127 + x0c] + w10 * rp[y0c * 127 + x1c] +
                 w01 * rp[y1c * 127 + x0c] + w11 * rp[y1c * 127 + x1c];
    sc[i] = acc * 0.17677669529663688f + bias;  // scale = 32^-0.5
  }

  // --- softmax over n=256 per query row ---
  float mx = -1e30f;
#pragma unroll
  for (int i = 0; i < 32; ++i) mx = fmaxf(mx, sc[i]);
  mx = fmaxf(mx, __shfl_xor(mx, 32));
  if ((tid & 32) == 0) s_red[(tid >> 6) * 32 + mi] = mx;
  __syncthreads();  // also guarantees all k reads done before P overwrites
  float M = fmaxf(fmaxf(s_red[mi], s_red[32 + mi]),
                  fmaxf(s_red[64 + mi], s_red[96 + mi]));
  float sm = 0.f;
#pragma unroll
  for (int i = 0; i < 32; ++i) {
    sc[i] = __expf(sc[i] - M);
    sm += sc[i];
  }
  sm += __shfl_xor(sm, 32);
  if ((tid & 32) == 0) s_red2[(tid >> 6) * 32 + mi] = sm;
  __syncthreads();
  float S = s_red2[mi] + s_red2[32 + mi] + s_red2[64 + mi] + s_red2[96 + mi];
  float inv = 1.f / S;
#pragma unroll
  for (int i = 0; i < 32; ++i) s_kp[mi * 260 + ng * 32 + i] = sc[i] * inv;
  __syncthreads();

  // --- PV: thread (mi, cg) -> out[cg*4+j][m0+mi] ---
  int cg = tid >> 5;
  float acc[4] = {0.f, 0.f, 0.f, 0.f};
  const float* vrow0 = vg + (size_t)(cg * 4) * 256;
  for (int n = 0; n < 256; n += 4) {
    float4 pv = *(const float4*)&s_kp[mi * 260 + n];
#pragma unroll
    for (int j = 0; j < 4; ++j) {
      float4 vv = *(const float4*)&vrow0[(size_t)j * 256 + n];
      acc[j] += pv.x * vv.x + pv.y * vv.y + pv.z * vv.z + pv.w * vv.w;
    }
  }
  float* ob = out + (size_t)(b * NCH + h * 32 + cg * 4) * HW + m0 + mi;
#pragma unroll
  for (int j = 0; j < 4; ++j) ob[(size_t)j * HW] = acc[j];
}

// ---------------------------------------------------------------------------
// launch
// ---------------------------------------------------------------------------
extern "C" void kernel_launch(void* const* d_in, const int* in_sizes, int n_in,
                              void* d_out, int out_size, void* d_ws,
                              size_t ws_size, hipStream_t stream) {
  const float* x = (const float*)d_in[0];
  const float* w_dw = (const float*)d_in[1];
  const float* ln_w = (const float*)d_in[2];
  const float* w_off = (const float*)d_in[3];
  const float* wq = (const float*)d_in[4];
  const float* wk = (const float*)d_in[5];
  const float* wv = (const float*)d_in[6];
  const float* wo = (const float*)d_in[7];
  const float* rpe = (const float*)d_in[8];
  float* out = (float*)d_out;
  float* ws = (float*)d_ws;

  // q lives in d_out until the final conv overwrites it (saves 16 MB of ws).
  float* q = out;
  float* attn_out = ws;             // 8*128*4096   = 4194304 floats
  float* xs = ws + 4194304;         // 8*128*256    = 262144
  float* kbuf = ws + 4456448;       // 262144
  float* vbuf = ws + 4718592;       // 262144
  float* pos = ws + 4980736;        // 16*256*2     = 8192
  float* dm = ws + 4988928;         // 16*256       = 4096
  // total = 4993024 floats ~= 19.1 MiB of d_ws

  conv1x1_kernel<<<dim3(16, 8, 4), 256, 0, stream>>>(x, wq, q);
  conv_offset_kernel<<<dim3(256, 16), 64, 0, stream>>>(q, w_dw, ln_w, w_off,
                                                       pos, dm);
  sample_xs_kernel<<<16, 256, 0, stream>>>(x, pos, dm, xs);
  kv_kernel<<<dim3(16, 8, 2), 256, 0, stream>>>(xs, wk, wv, kbuf, vbuf);
  attn_kernel<<<dim3(128, 32), 256, 0, stream>>>(q, kbuf, vbuf, pos, rpe,
                                                 attn_out);
  conv1x1_kernel<<<dim3(16, 8, 4), 256, 0, stream>>>(attn_out, wo, out);
}

// Round 2
// 341.632 us; speedup vs baseline: 1.2853x; 1.2853x over previous
//
#include <hip/hip_runtime.h>
#include <hip/hip_bf16.h>
#include <math.h>

// Problem constants (B=8, C=128, H=W=64, G=2, gc=64, nH=4, dh=32, Hk=Wk=16, n=256)
#define HW 4096
#define NCH 128

typedef __attribute__((ext_vector_type(8))) short short8;
typedef __attribute__((ext_vector_type(4))) float f32x4;

__device__ __forceinline__ short f2bf(float f) {
  union { __hip_bfloat16 h; short s; } u;
  u.h = __float2bfloat16(f);
  return u.s;
}

// ---------------------------------------------------------------------------
// K1/K6: 1x1 conv (C=128 -> 128 GEMM over 4096 positions per batch), fp32.
// ---------------------------------------------------------------------------
__global__ __launch_bounds__(256) void conv1x1_kernel(
    const float* __restrict__ x, const float* __restrict__ w,
    float* __restrict__ out) {
  int tid = threadIdx.x;
  int p = blockIdx.x * 256 + tid;
  int b = blockIdx.y;
  int o0 = blockIdx.z * 32;
  const float* xp = x + (size_t)b * NCH * HW + p;
  float acc[32];
#pragma unroll
  for (int j = 0; j < 32; ++j) acc[j] = 0.f;
  for (int i = 0; i < NCH; i += 4) {
    float x0 = xp[(size_t)(i + 0) * HW];
    float x1 = xp[(size_t)(i + 1) * HW];
    float x2 = xp[(size_t)(i + 2) * HW];
    float x3 = xp[(size_t)(i + 3) * HW];
#pragma unroll
    for (int j = 0; j < 32; ++j) {
      const float* wr = w + (o0 + j) * NCH + i;
      acc[j] += wr[0] * x0 + wr[1] * x1 + wr[2] * x2 + wr[3] * x3;
    }
  }
  float* op = out + (size_t)b * NCH * HW + (size_t)o0 * HW + p;
#pragma unroll
  for (int j = 0; j < 32; ++j) op[(size_t)j * HW] = acc[j];
}

// ---------------------------------------------------------------------------
// K2: conv_offset fused: depthwise 5x5 s4 p2 -> BiasFree LN -> GELU -> 1x1(3)
//     -> tanh/sigmoid -> pos (y,x) + dm.  One wave (64 ch) per (bg, p).
// ---------------------------------------------------------------------------
__device__ __forceinline__ float wsum64(float v) {
#pragma unroll
  for (int o = 32; o > 0; o >>= 1) v += __shfl_xor(v, o);
  return v;
}

__global__ __launch_bounds__(64) void conv_offset_kernel(
    const float* __restrict__ q, const float* __restrict__ w_dw,
    const float* __restrict__ ln_w, const float* __restrict__ w_off,
    float* __restrict__ pos, float* __restrict__ dm) {
  int c = threadIdx.x;       // 0..63
  int p = blockIdx.x;        // 0..255
  int bg = blockIdx.y;       // 0..15
  int py = p >> 4, px = p & 15;
  const float* qp = q + (size_t)((bg >> 1) * NCH + (bg & 1) * 64 + c) * HW;
  const float* wd = w_dw + c * 25;
  float acc = 0.f;
#pragma unroll
  for (int ky = 0; ky < 5; ++ky) {
    int iy = 4 * py + ky - 2;
    if (iy < 0 || iy >= 64) continue;
#pragma unroll
    for (int kx = 0; kx < 5; ++kx) {
      int ix = 4 * px + kx - 2;
      if (ix < 0 || ix >= 64) continue;
      acc += wd[ky * 5 + kx] * qp[iy * 64 + ix];
    }
  }
  float mean = wsum64(acc) * (1.f / 64.f);
  float msq = wsum64(acc * acc) * (1.f / 64.f);
  float var = msq - mean * mean;                    // jnp.var (ddof=0)
  float g = acc * rsqrtf(var + 1e-5f) * ln_w[c];    // BiasFree LN
  g = 0.5f * g * (1.f + erff(g * 0.70710678118654752f));  // exact GELU
  float o0 = wsum64(w_off[c] * g);
  float o1 = wsum64(w_off[64 + c] * g);
  float o2 = wsum64(w_off[128 + c] * g);
  if (c == 0) {
    int idx = bg * 256 + p;
    float posy = tanhf(o0) * (1.f / 16.f) + ((py + 0.5f) * (1.f / 8.f) - 1.f);
    float posx = tanhf(o1) * (1.f / 16.f) + ((px + 0.5f) * (1.f / 8.f) - 1.f);
    pos[idx * 2] = posy;
    pos[idx * 2 + 1] = posx;
    dm[idx] = 1.f / (1.f + expf(-o2));
  }
}

// ---------------------------------------------------------------------------
// K3: xs = grid_sample(x, pos) * dm   (align_corners=True, zeros padding)
// grid (16 bg, 64 c), 256 threads = sample positions.
// ---------------------------------------------------------------------------
__global__ __launch_bounds__(256) void sample_xs_kernel(
    const float* __restrict__ x, const float* __restrict__ pos,
    const float* __restrict__ dm, float* __restrict__ xs) {
  int p = threadIdx.x;
  int bg = blockIdx.x;
  int c = blockIdx.y;  // 0..63
  int idx = bg * 256 + p;
  float posy = pos[idx * 2], posx = pos[idx * 2 + 1];
  float dmv = dm[idx];
  float gx = (posx + 1.f) * 31.5f;   // (g+1)*0.5*(64-1)
  float gy = (posy + 1.f) * 31.5f;
  float x0f = floorf(gx), y0f = floorf(gy);
  int ix = (int)x0f, iy = (int)y0f;
  float fx = gx - x0f, fy = gy - y0f;
  float w00 = (1.f - fx) * (1.f - fy), w10 = fx * (1.f - fy);
  float w01 = (1.f - fx) * fy, w11 = fx * fy;
  bool vx0 = (ix >= 0 && ix < 64), vx1 = (ix + 1 >= 0 && ix + 1 < 64);
  bool vy0 = (iy >= 0 && iy < 64), vy1 = (iy + 1 >= 0 && iy + 1 < 64);
  if (!(vx0 && vy0)) w00 = 0.f;
  if (!(vx1 && vy0)) w10 = 0.f;
  if (!(vx0 && vy1)) w01 = 0.f;
  if (!(vx1 && vy1)) w11 = 0.f;
  int x0c = min(max(ix, 0), 63), x1c = min(max(ix + 1, 0), 63);
  int y0c = min(max(iy, 0), 63), y1c = min(max(iy + 1, 0), 63);
  const float* img = x + ((size_t)(bg >> 1) * NCH + (bg & 1) * 64 + c) * HW;
  float v = w00 * img[y0c * 64 + x0c] + w10 * img[y0c * 64 + x1c] +
            w01 * img[y1c * 64 + x0c] + w11 * img[y1c * 64 + x1c];
  xs[((size_t)(bg >> 1) * NCH + (bg & 1) * 64 + c) * 256 + p] = v * dmv;
}

// ---------------------------------------------------------------------------
// K4: k,v 1x1 conv -> bf16 in MFMA-friendly layouts.
//   kbf[bh][n][dh] (A-operand rows), vbf[bh][c][n] (A-operand rows).
// grid (128 o, 8 b, 2 which), 256 threads = n.
// ---------------------------------------------------------------------------
__global__ __launch_bounds__(256) void kv_kernel(
    const float* __restrict__ xs, const float* __restrict__ wk,
    const float* __restrict__ wv, short* __restrict__ kbf,
    short* __restrict__ vbf) {
  int p = threadIdx.x;
  int o = blockIdx.x;
  int b = blockIdx.y;
  const float* w = blockIdx.z ? wv : wk;
  const float* xp = xs + (size_t)b * NCH * 256 + p;
  const float* wr = w + o * NCH;
  float acc = 0.f;
  for (int i = 0; i < NCH; i += 4) {
    acc += wr[i] * xp[i * 256] + wr[i + 1] * xp[(i + 1) * 256] +
           wr[i + 2] * xp[(i + 2) * 256] + wr[i + 3] * xp[(i + 3) * 256];
  }
  int h = o >> 5, dh = o & 31;
  if (blockIdx.z)
    vbf[((size_t)(b * 4 + h) * 32 + dh) * 256 + p] = f2bf(acc);
  else
    kbf[((size_t)(b * 4 + h) * 256 + p) * 32 + dh] = f2bf(acc);
}

// ---------------------------------------------------------------------------
// K5: MFMA attention. Block = 64 queries x (b*4+h); wave = 16 queries.
// S^T = K·Q^T via 16x16x32 bf16 MFMA (C-layout: rows=n, cols=m) ->
// bias (bilinear RPE, fp32 VALU) -> softmax (in-lane over 64 regs +
// shfl_xor 16/32) -> P to LDS bf16 [m][264] -> PV = V·P via 16 MFMAs.
// ---------------------------------------------------------------------------
#define PROW 264  // bf16 elems per P row: 528B = 33*16 (b128-aligned, 2-way banks)

__global__ __launch_bounds__(256) void attn_kernel(
    const float* __restrict__ q, const short* __restrict__ kbf,
    const short* __restrict__ vbf, const float* __restrict__ pos,
    const float* __restrict__ rpe, float* __restrict__ out) {
  __shared__ __align__(16) short s_p[4 * 16 * PROW];  // per-wave P [16m][PROW]
  __shared__ float s_pos[512];

  int tid = threadIdx.x;
  int wv = tid >> 6;
  int lane = tid & 63;
  int l15 = lane & 15;
  int qd = lane >> 4;  // quad 0..3
  int bh = blockIdx.y;
  int b = bh >> 2, h = bh & 3;
  int bg = b * 2 + (h >> 1);
  int m0 = blockIdx.x * 64 + wv * 16;

  s_pos[tid] = pos[(size_t)bg * 512 + tid];
  s_pos[256 + tid] = pos[(size_t)bg * 512 + 256 + tid];
  __syncthreads();

  // Q B-fragment: Q^T[k=qd*8+j][m=l15] from fp32 q (channel-major)
  short8 qfrag;
  {
    const float* qg = q + ((size_t)(b * NCH + h * 32 + qd * 8)) * HW + m0 + l15;
#pragma unroll
    for (int j = 0; j < 8; ++j) qfrag[j] = f2bf(qg[(size_t)j * HW]);
  }

  // S^T tiles: A = K[16n x 32dh] per tile
  f32x4 acc[16];
  {
    const short* kb = kbf + ((size_t)bh * 256 + l15) * 32 + qd * 8;
#pragma unroll
    for (int t = 0; t < 16; ++t) {
      short8 kf = *(const short8*)(kb + t * 16 * 32);
      acc[t] = __builtin_amdgcn_mfma_f32_16x16x32_bf16(
          kf, qfrag, (f32x4){0.f, 0.f, 0.f, 0.f}, 0, 0, 0);
    }
  }

  // scale + RPE bias + running max.  Element (t,r): n = t*16+qd*4+r, m fixed.
  int m = m0 + l15;
  float gy0 = ((((float)(m >> 6) + 0.5f) * (1.f / 32.f) - 1.f) * 0.5f + 1.f) * 63.f;
  float gx0 = ((((float)(m & 63) + 0.5f) * (1.f / 32.f) - 1.f) * 0.5f + 1.f) * 63.f;
  const float* rp = rpe + (size_t)h * (127 * 127);
  float mx = -1e30f;
#pragma unroll
  for (int t = 0; t < 16; ++t) {
#pragma unroll
    for (int r = 0; r < 4; ++r) {
      int n = t * 16 + qd * 4 + r;
      float2 pp = *(const float2*)&s_pos[n * 2];  // (py, px), quad-broadcast
      float gy = gy0 - pp.x * 31.5f;
      float gx = gx0 - pp.y * 31.5f;
      float y0f = floorf(gy), x0f = floorf(gx);
      int iy = (int)y0f, ix = (int)x0f;
      float fy = gy - y0f, fx = gx - x0f;
      float w00 = (1.f - fx) * (1.f - fy), w10 = fx * (1.f - fy);
      float w01 = (1.f - fx) * fy, w11 = fx * fy;
      bool vx0 = (unsigned)ix < 127u, vx1 = (unsigned)(ix + 1) < 127u;
      bool vy0 = (unsigned)iy < 127u, vy1 = (unsigned)(iy + 1) < 127u;
      if (!(vx0 && vy0)) w00 = 0.f;
      if (!(vx1 && vy0)) w10 = 0.f;
      if (!(vx0 && vy1)) w01 = 0.f;
      if (!(vx1 && vy1)) w11 = 0.f;
      int x0c = min(max(ix, 0), 126), x1c = min(max(ix + 1, 0), 126);
      int y0c = min(max(iy, 0), 126), y1c = min(max(iy + 1, 0), 126);
      float bias = w00 * rp[y0c * 127 + x0c] + w10 * rp[y0c * 127 + x1c] +
                   w01 * rp[y1c * 127 + x0c] + w11 * rp[y1c * 127 + x1c];
      float s = acc[t][r] * 0.17677669529663688f + bias;
      acc[t][r] = s;
      mx = fmaxf(mx, s);
    }
  }
  mx = fmaxf(mx, __shfl_xor(mx, 16));
  float M = fmaxf(mx, __shfl_xor(mx, 32));

  float sm = 0.f;
#pragma unroll
  for (int t = 0; t < 16; ++t) {
#pragma unroll
    for (int r = 0; r < 4; ++r) {
      float e = __expf(acc[t][r] - M);
      acc[t][r] = e;
      sm += e;
    }
  }
  sm += __shfl_xor(sm, 16);
  sm += __shfl_xor(sm, 32);
  float inv = 1.f / sm;

  // write normalized P (bf16) to this wave's LDS region, layout [m][n]
  {
    short* pw = s_p + wv * 16 * PROW + l15 * PROW;
#pragma unroll
    for (int t = 0; t < 16; ++t) {
      int n = t * 16 + qd * 4;
      unsigned u0 = (unsigned short)f2bf(acc[t][0] * inv) |
                    ((unsigned)(unsigned short)f2bf(acc[t][1] * inv) << 16);
      unsigned u1 = (unsigned short)f2bf(acc[t][2] * inv) |
                    ((unsigned)(unsigned short)f2bf(acc[t][3] * inv) << 16);
      *(unsigned*)(pw + n) = u0;
      *(unsigned*)(pw + n + 2) = u1;
    }
  }
  __syncthreads();

  // PV: Out[c,m] = sum_n V[c,n] P[n,m]; A = V tiles, B = P from LDS
  f32x4 o0 = {0.f, 0.f, 0.f, 0.f}, o1 = {0.f, 0.f, 0.f, 0.f};
  {
    const short* vb = vbf + ((size_t)bh * 32 + l15) * 256 + qd * 8;
    const short* pr = s_p + wv * 16 * PROW + l15 * PROW + qd * 8;
#pragma unroll
    for (int ch = 0; ch < 8; ++ch) {
      short8 pf = *(const short8*)(pr + ch * 32);
      short8 v0 = *(const short8*)(vb + ch * 32);
      short8 v1 = *(const short8*)(vb + 16 * 256 + ch * 32);
      o0 = __builtin_amdgcn_mfma_f32_16x16x32_bf16(v0, pf, o0, 0, 0, 0);
      o1 = __builtin_amdgcn_mfma_f32_16x16x32_bf16(v1, pf, o1, 0, 0, 0);
    }
  }
  // D: row = c-offset = qd*4+reg, col = m = l15
  float* ob = out + ((size_t)(b * NCH + h * 32 + qd * 4)) * HW + m0 + l15;
#pragma unroll
  for (int r = 0; r < 4; ++r) {
    ob[(size_t)r * HW] = o0[r];
    ob[(size_t)(16 + r) * HW] = o1[r];
  }
}

// ---------------------------------------------------------------------------
// launch
// ---------------------------------------------------------------------------
extern "C" void kernel_launch(void* const* d_in, const int* in_sizes, int n_in,
                              void* d_out, int out_size, void* d_ws,
                              size_t ws_size, hipStream_t stream) {
  const float* x = (const float*)d_in[0];
  const float* w_dw = (const float*)d_in[1];
  const float* ln_w = (const float*)d_in[2];
  const float* w_off = (const float*)d_in[3];
  const float* wq = (const float*)d_in[4];
  const float* wk = (const float*)d_in[5];
  const float* wv = (const float*)d_in[6];
  const float* wo = (const float*)d_in[7];
  const float* rpe = (const float*)d_in[8];
  float* out = (float*)d_out;
  float* ws = (float*)d_ws;

  // q lives in d_out until the final conv overwrites it.
  // xs aliases attn_out's first 1 MB (xs is dead before attn_kernel runs).
  float* q = out;
  float* attn_out = ws;                     // 4194304 floats (16.7 MB)
  float* xs = ws;                           // 262144 floats, aliased (dead early)
  short* kbf = (short*)(ws + 4194304);      // 262144 bf16
  short* vbf = kbf + 262144;                // 262144 bf16
  float* pos = (float*)(vbf + 262144);      // 8192 floats
  float* dm = pos + 8192;                   // 4096 floats
  // total ~17.9 MB of d_ws

  conv1x1_kernel<<<dim3(16, 8, 4), 256, 0, stream>>>(x, wq, q);
  conv_offset_kernel<<<dim3(256, 16), 64, 0, stream>>>(q, w_dw, ln_w, w_off,
                                                       pos, dm);
  sample_xs_kernel<<<dim3(16, 64), 256, 0, stream>>>(x, pos, dm, xs);
  kv_kernel<<<dim3(128, 8, 2), 256, 0, stream>>>(xs, wk, wv, kbf, vbf);
  attn_kernel<<<dim3(64, 32), 256, 0, stream>>>(q, kbf, vbf, pos, rpe,
                                                attn_out);
  conv1x1_kernel<<<dim3(16, 8, 4), 256, 0, stream>>>(attn_out, wo, out);
}

// Round 3
// 274.948 us; speedup vs baseline: 1.5971x; 1.2425x over previous
//
#include <hip/hip_runtime.h>
#include <hip/hip_bf16.h>
#include <math.h>

// Problem constants (B=8, C=128, H=W=64, G=2, gc=64, nH=4, dh=32, Hk=Wk=16, n=256)
#define HW 4096
#define NCH 128

typedef __attribute__((ext_vector_type(8))) short short8;
typedef __attribute__((ext_vector_type(4))) float f32x4;

__device__ __forceinline__ short f2bf(float f) {
  union { __hip_bfloat16 h; short s; } u;
  u.h = __float2bfloat16(f);
  return u.s;
}

// ---------------------------------------------------------------------------
// K0: convert wo (128x128 fp32) to bf16 row-major
// ---------------------------------------------------------------------------
__global__ __launch_bounds__(256) void wcvt_kernel(const float* __restrict__ w,
                                                   short* __restrict__ wbf) {
  int i = blockIdx.x * 256 + threadIdx.x;
  wbf[i] = f2bf(w[i]);
}

// ---------------------------------------------------------------------------
// K1: q = wq*x, 1x1 conv fp32 (q must stay fp32: pos path amplifies error 31.5x)
// ---------------------------------------------------------------------------
__global__ __launch_bounds__(256) void conv1x1_kernel(
    const float* __restrict__ x, const float* __restrict__ w,
    float* __restrict__ out) {
  int tid = threadIdx.x;
  int p = blockIdx.x * 256 + tid;
  int b = blockIdx.y;
  int o0 = blockIdx.z * 32;
  const float* xp = x + (size_t)b * NCH * HW + p;
  float acc[32];
#pragma unroll
  for (int j = 0; j < 32; ++j) acc[j] = 0.f;
#pragma unroll 2
  for (int i = 0; i < NCH; i += 4) {
    float x0 = xp[(size_t)(i + 0) * HW];
    float x1 = xp[(size_t)(i + 1) * HW];
    float x2 = xp[(size_t)(i + 2) * HW];
    float x3 = xp[(size_t)(i + 3) * HW];
#pragma unroll
    for (int j = 0; j < 32; ++j) {
      const float* wr = w + (o0 + j) * NCH + i;
      acc[j] += wr[0] * x0 + wr[1] * x1 + wr[2] * x2 + wr[3] * x3;
    }
  }
  float* op = out + (size_t)b * NCH * HW + (size_t)o0 * HW + p;
#pragma unroll
  for (int j = 0; j < 32; ++j) op[(size_t)j * HW] = acc[j];
}

// ---------------------------------------------------------------------------
// K2: conv_offset fused: depthwise 5x5 s4 p2 -> BiasFree LN -> GELU -> 1x1(3)
//     -> tanh/sigmoid -> pos (y,x) + dm.  One wave (64 ch) per (bg, p).
// ---------------------------------------------------------------------------
__device__ __forceinline__ float wsum64(float v) {
#pragma unroll
  for (int o = 32; o > 0; o >>= 1) v += __shfl_xor(v, o);
  return v;
}

__global__ __launch_bounds__(64) void conv_offset_kernel(
    const float* __restrict__ q, const float* __restrict__ w_dw,
    const float* __restrict__ ln_w, const float* __restrict__ w_off,
    float* __restrict__ pos, float* __restrict__ dm) {
  int c = threadIdx.x;       // 0..63
  int p = blockIdx.x;        // 0..255
  int bg = blockIdx.y;       // 0..15
  int py = p >> 4, px = p & 15;
  const float* qp = q + (size_t)((bg >> 1) * NCH + (bg & 1) * 64 + c) * HW;
  const float* wd = w_dw + c * 25;
  float acc = 0.f;
#pragma unroll
  for (int ky = 0; ky < 5; ++ky) {
    int iy = 4 * py + ky - 2;
    if (iy < 0 || iy >= 64) continue;
#pragma unroll
    for (int kx = 0; kx < 5; ++kx) {
      int ix = 4 * px + kx - 2;
      if (ix < 0 || ix >= 64) continue;
      acc += wd[ky * 5 + kx] * qp[iy * 64 + ix];
    }
  }
  float mean = wsum64(acc) * (1.f / 64.f);
  float msq = wsum64(acc * acc) * (1.f / 64.f);
  float var = msq - mean * mean;                    // jnp.var (ddof=0)
  float g = acc * rsqrtf(var + 1e-5f) * ln_w[c];    // BiasFree LN
  g = 0.5f * g * (1.f + erff(g * 0.70710678118654752f));  // exact GELU
  float o0 = wsum64(w_off[c] * g);
  float o1 = wsum64(w_off[64 + c] * g);
  float o2 = wsum64(w_off[128 + c] * g);
  if (c == 0) {
    int idx = bg * 256 + p;
    float posy = tanhf(o0) * (1.f / 16.f) + ((py + 0.5f) * (1.f / 8.f) - 1.f);
    float posx = tanhf(o1) * (1.f / 16.f) + ((px + 0.5f) * (1.f / 8.f) - 1.f);
    pos[idx * 2] = posy;
    pos[idx * 2 + 1] = posx;
    dm[idx] = 1.f / (1.f + expf(-o2));
  }
}

// ---------------------------------------------------------------------------
// K3: xs = grid_sample(x, pos) * dm   (align_corners=True, zeros padding)
// grid (16 bg, 64 c), 256 threads = sample positions.
// Masks kept: tanhf can saturate to exactly +/-1 -> gx can hit 63.0 edge.
// ---------------------------------------------------------------------------
__global__ __launch_bounds__(256) void sample_xs_kernel(
    const float* __restrict__ x, const float* __restrict__ pos,
    const float* __restrict__ dm, float* __restrict__ xs) {
  int p = threadIdx.x;
  int bg = blockIdx.x;
  int c = blockIdx.y;  // 0..63
  int idx = bg * 256 + p;
  float posy = pos[idx * 2], posx = pos[idx * 2 + 1];
  float dmv = dm[idx];
  float gx = (posx + 1.f) * 31.5f;   // (g+1)*0.5*(64-1)
  float gy = (posy + 1.f) * 31.5f;
  float x0f = floorf(gx), y0f = floorf(gy);
  int ix = (int)x0f, iy = (int)y0f;
  float fx = gx - x0f, fy = gy - y0f;
  float w00 = (1.f - fx) * (1.f - fy), w10 = fx * (1.f - fy);
  float w01 = (1.f - fx) * fy, w11 = fx * fy;
  bool vx0 = (ix >= 0 && ix < 64), vx1 = (ix + 1 >= 0 && ix + 1 < 64);
  bool vy0 = (iy >= 0 && iy < 64), vy1 = (iy + 1 >= 0 && iy + 1 < 64);
  if (!(vx0 && vy0)) w00 = 0.f;
  if (!(vx1 && vy0)) w10 = 0.f;
  if (!(vx0 && vy1)) w01 = 0.f;
  if (!(vx1 && vy1)) w11 = 0.f;
  int x0c = min(max(ix, 0), 63), x1c = min(max(ix + 1, 0), 63);
  int y0c = min(max(iy, 0), 63), y1c = min(max(iy + 1, 0), 63);
  const float* img = x + ((size_t)(bg >> 1) * NCH + (bg & 1) * 64 + c) * HW;
  float v = w00 * img[y0c * 64 + x0c] + w10 * img[y0c * 64 + x1c] +
            w01 * img[y1c * 64 + x0c] + w11 * img[y1c * 64 + x1c];
  xs[((size_t)(bg >> 1) * NCH + (bg & 1) * 64 + c) * 256 + p] = v * dmv;
}

// ---------------------------------------------------------------------------
// K4: k,v 1x1 conv -> bf16 in MFMA-friendly layouts.
//   kbf[bh][n][dh] (A-operand rows), vbf[bh][c][n] (A-operand rows).
// ---------------------------------------------------------------------------
__global__ __launch_bounds__(256) void kv_kernel(
    const float* __restrict__ xs, const float* __restrict__ wk,
    const float* __restrict__ wv, short* __restrict__ kbf,
    short* __restrict__ vbf) {
  int p = threadIdx.x;
  int o = blockIdx.x;
  int b = blockIdx.y;
  const float* w = blockIdx.z ? wv : wk;
  const float* xp = xs + (size_t)b * NCH * 256 + p;
  const float* wr = w + o * NCH;
  float acc = 0.f;
#pragma unroll 2
  for (int i = 0; i < NCH; i += 4) {
    acc += wr[i] * xp[i * 256] + wr[i + 1] * xp[(i + 1) * 256] +
           wr[i + 2] * xp[(i + 2) * 256] + wr[i + 3] * xp[(i + 3) * 256];
  }
  int h = o >> 5, dh = o & 31;
  if (blockIdx.z)
    vbf[((size_t)(b * 4 + h) * 32 + dh) * 256 + p] = f2bf(acc);
  else
    kbf[((size_t)(b * 4 + h) * 256 + p) * 32 + dh] = f2bf(acc);
}

// ---------------------------------------------------------------------------
// K5: MFMA attention with LDS-staged RPE table.
// s_buf holds rpe[h] (127*127 fp32 = 64516 B) during phase A; after a barrier
// it is overlaid by P (bf16, per-wave [16m][PROW]).  pos read from L1
// (quad-uniform -> broadcast).  Range analysis: pos in (-1,1), qg in
// [-.984,.984] -> rpe coords in (0.5,125.5): no OOB masks needed.
// Output written directly as bf16 [b][m][c] for the MFMA wo-conv.
// ---------------------------------------------------------------------------
#define PROW 264  // bf16 elems per P row (528 B, 16B-aligned rows)

__global__ __launch_bounds__(256) void attn_kernel(
    const float* __restrict__ q, const short* __restrict__ kbf,
    const short* __restrict__ vbf, const float* __restrict__ pos,
    const float* __restrict__ rpe, short* __restrict__ outT) {
  __shared__ __align__(16) float s_buf[127 * 127];  // 64516 B (<= 65536)

  int tid = threadIdx.x;
  int wv = tid >> 6;
  int lane = tid & 63;
  int l15 = lane & 15;
  int qd = lane >> 4;  // quad 0..3
  int bh = blockIdx.y;
  int b = bh >> 2, h = bh & 3;
  int bg = b * 2 + (h >> 1);
  int m0 = blockIdx.x * 64 + wv * 16;

  // stage rpe[h] into LDS (coalesced, 63 iters/thread)
  {
    const float* rp = rpe + (size_t)h * (127 * 127);
    for (int i = tid; i < 127 * 127; i += 256) s_buf[i] = rp[i];
  }

  // Q B-fragment: Q^T[k=qd*8+j][m=l15] from fp32 q (channel-major)
  short8 qfrag;
  {
    const float* qg = q + ((size_t)(b * NCH + h * 32 + qd * 8)) * HW + m0 + l15;
#pragma unroll
    for (int j = 0; j < 8; ++j) qfrag[j] = f2bf(qg[(size_t)j * HW]);
  }

  // S^T tiles: A = K[16n x 32dh] per tile (no LDS involved)
  f32x4 acc[16];
  {
    const short* kb = kbf + ((size_t)bh * 256 + l15) * 32 + qd * 8;
#pragma unroll
    for (int t = 0; t < 16; ++t) {
      short8 kf = *(const short8*)(kb + t * 16 * 32);
      acc[t] = __builtin_amdgcn_mfma_f32_16x16x32_bf16(
          kf, qfrag, (f32x4){0.f, 0.f, 0.f, 0.f}, 0, 0, 0);
    }
  }
  __syncthreads();  // rpe staged

  // scale + RPE bias + running max.  Element (t,r): n = t*16+qd*4+r, m fixed.
  int m = m0 + l15;
  float gy0 = ((((float)(m >> 6) + 0.5f) * (1.f / 32.f) - 1.f) * 0.5f + 1.f) * 63.f;
  float gx0 = ((((float)(m & 63) + 0.5f) * (1.f / 32.f) - 1.f) * 0.5f + 1.f) * 63.f;
  const float* posg = pos + (size_t)bg * 512;
  float mx = -1e30f;
#pragma unroll
  for (int t = 0; t < 16; ++t) {
#pragma unroll
    for (int r = 0; r < 4; ++r) {
      int n = t * 16 + qd * 4 + r;
      float2 pp = *(const float2*)&posg[n * 2];  // L1-hot, quad-broadcast
      float gy = gy0 - pp.x * 31.5f;
      float gx = gx0 - pp.y * 31.5f;
      float y0f = floorf(gy), x0f = floorf(gx);
      float fy = gy - y0f, fx = gx - x0f;
      int base = (int)y0f * 127 + (int)x0f;
      float t00 = s_buf[base], t10 = s_buf[base + 1];
      float t01 = s_buf[base + 127], t11 = s_buf[base + 128];
      float r0 = t00 + fx * (t10 - t00);
      float r1 = t01 + fx * (t11 - t01);
      float bias = r0 + fy * (r1 - r0);
      float s = acc[t][r] * 0.17677669529663688f + bias;  // scale = 32^-0.5
      acc[t][r] = s;
      mx = fmaxf(mx, s);
    }
  }
  mx = fmaxf(mx, __shfl_xor(mx, 16));
  float M = fmaxf(mx, __shfl_xor(mx, 32));

  float sm = 0.f;
#pragma unroll
  for (int t = 0; t < 16; ++t) {
#pragma unroll
    for (int r = 0; r < 4; ++r) {
      float e = __expf(acc[t][r] - M);
      acc[t][r] = e;
      sm += e;
    }
  }
  sm += __shfl_xor(sm, 16);
  sm += __shfl_xor(sm, 32);
  float inv = 1.f / sm;

  __syncthreads();  // all rpe reads done before P overlays s_buf

  // write normalized P (bf16) to this wave's region of s_buf, layout [m][n]
  short* s_p = (short*)s_buf;
  {
    short* pw = s_p + wv * 16 * PROW + l15 * PROW;
#pragma unroll
    for (int t = 0; t < 16; ++t) {
      int n = t * 16 + qd * 4;
      unsigned u0 = (unsigned short)f2bf(acc[t][0] * inv) |
                    ((unsigned)(unsigned short)f2bf(acc[t][1] * inv) << 16);
      unsigned u1 = (unsigned short)f2bf(acc[t][2] * inv) |
                    ((unsigned)(unsigned short)f2bf(acc[t][3] * inv) << 16);
      *(unsigned*)(pw + n) = u0;
      *(unsigned*)(pw + n + 2) = u1;
    }
  }
  // no barrier: each wave reads only its own P region (intra-wave lgkmcnt)

  // PV: Out[c,m] = sum_n V[c,n] P[n,m]; A = V tiles, B = P from LDS
  f32x4 o0 = {0.f, 0.f, 0.f, 0.f}, o1 = {0.f, 0.f, 0.f, 0.f};
  {
    const short* vb = vbf + ((size_t)bh * 32 + l15) * 256 + qd * 8;
    const short* pr = s_p + wv * 16 * PROW + l15 * PROW + qd * 8;
#pragma unroll
    for (int ch = 0; ch < 8; ++ch) {
      short8 pf = *(const short8*)(pr + ch * 32);
      short8 v0 = *(const short8*)(vb + ch * 32);
      short8 v1 = *(const short8*)(vb + 16 * 256 + ch * 32);
      o0 = __builtin_amdgcn_mfma_f32_16x16x32_bf16(v0, pf, o0, 0, 0, 0);
      o1 = __builtin_amdgcn_mfma_f32_16x16x32_bf16(v1, pf, o1, 0, 0, 0);
    }
  }
  // D row = c-offset = qd*4+r, col = m = l15.  Write bf16 [b][m][c] packed.
  {
    size_t row = (size_t)(b * HW + m0 + l15) * NCH + h * 32 + qd * 4;
    short4 s0, s1;
    s0.x = f2bf(o0[0]); s0.y = f2bf(o0[1]); s0.z = f2bf(o0[2]); s0.w = f2bf(o0[3]);
    s1.x = f2bf(o1[0]); s1.y = f2bf(o1[1]); s1.z = f2bf(o1[2]); s1.w = f2bf(o1[3]);
    *(short4*)&outT[row] = s0;
    *(short4*)&outT[row + 16] = s1;
  }
}

// ---------------------------------------------------------------------------
// K6: final conv via MFMA: out[b][o][m] = sum_c wo[o][c] * attnT[b][m][c]
// A = attnT tile [16m x 32c] (contiguous 16B/lane), B = wo^T (row l15 of
// wo_bf, contiguous).  Wave = 16 m-rows x all 128 o.  4 waves/block.
// ---------------------------------------------------------------------------
__global__ __launch_bounds__(256) void wo_mfma_kernel(
    const short* __restrict__ attnT, const short* __restrict__ wo_bf,
    float* __restrict__ out) {
  int tid = threadIdx.x;
  int wv = tid >> 6;
  int lane = tid & 63;
  int l15 = lane & 15;
  int qd = lane >> 4;
  int b = blockIdx.x >> 6;
  int m0 = (blockIdx.x & 63) * 64 + wv * 16;

  f32x4 acc[8];
#pragma unroll
  for (int ot = 0; ot < 8; ++ot) acc[ot] = (f32x4){0.f, 0.f, 0.f, 0.f};

  const short* arow = attnT + (size_t)(b * HW + m0 + l15) * NCH + qd * 8;
  const short* wrow = wo_bf + (size_t)l15 * NCH + qd * 8;
#pragma unroll
  for (int kc = 0; kc < 4; ++kc) {
    short8 afrag = *(const short8*)(arow + kc * 32);
#pragma unroll
    for (int ot = 0; ot < 8; ++ot) {
      short8 bfrag = *(const short8*)(wrow + (size_t)ot * 16 * NCH + kc * 32);
      acc[ot] = __builtin_amdgcn_mfma_f32_16x16x32_bf16(afrag, bfrag, acc[ot],
                                                        0, 0, 0);
    }
  }
  // D row = m (qd*4+r), col = o (l15): float4 store per o-tile
#pragma unroll
  for (int ot = 0; ot < 8; ++ot) {
    float* op = out + ((size_t)b * NCH + ot * 16 + l15) * HW + m0 + qd * 4;
    *(f32x4*)op = acc[ot];
  }
}

// ---------------------------------------------------------------------------
// launch
// ---------------------------------------------------------------------------
extern "C" void kernel_launch(void* const* d_in, const int* in_sizes, int n_in,
                              void* d_out, int out_size, void* d_ws,
                              size_t ws_size, hipStream_t stream) {
  const float* x = (const float*)d_in[0];
  const float* w_dw = (const float*)d_in[1];
  const float* ln_w = (const float*)d_in[2];
  const float* w_off = (const float*)d_in[3];
  const float* wq = (const float*)d_in[4];
  const float* wk = (const float*)d_in[5];
  const float* wv = (const float*)d_in[6];
  const float* wo = (const float*)d_in[7];
  const float* rpe = (const float*)d_in[8];
  float* out = (float*)d_out;
  float* ws = (float*)d_ws;

  // q lives in d_out until wo_mfma overwrites it (q is dead by then).
  // xs (fp32, 1 MB) aliases outT's start: xs is dead before attn writes outT.
  float* q = out;
  short* outT = (short*)ws;                 // 4194304 bf16 (8.4 MB)
  float* xs = ws;                           // 262144 fp32, aliased
  short* kbf = (short*)ws + 4194304;        // 262144 bf16
  short* vbf = kbf + 262144;                // 262144 bf16
  short* wo_bf = vbf + 262144;              // 16384 bf16
  float* pos = (float*)(wo_bf + 16384);     // 8192 fp32
  float* dm = pos + 8192;                   // 4096 fp32

  wcvt_kernel<<<64, 256, 0, stream>>>(wo, wo_bf);
  conv1x1_kernel<<<dim3(16, 8, 4), 256, 0, stream>>>(x, wq, q);
  conv_offset_kernel<<<dim3(256, 16), 64, 0, stream>>>(q, w_dw, ln_w, w_off,
                                                       pos, dm);
  sample_xs_kernel<<<dim3(16, 64), 256, 0, stream>>>(x, pos, dm, xs);
  kv_kernel<<<dim3(128, 8, 2), 256, 0, stream>>>(xs, wk, wv, kbf, vbf);
  attn_kernel<<<dim3(64, 32), 256, 0, stream>>>(q, kbf, vbf, pos, rpe, outT);
  wo_mfma_kernel<<<512, 256, 0, stream>>>(outT, wo_bf, out);
}

// Round 4
// 210.341 us; speedup vs baseline: 2.0876x; 1.3072x over previous
//
#include <hip/hip_runtime.h>
#include <hip/hip_bf16.h>
#include <math.h>

// Problem constants (B=8, C=128, H=W=64, G=2, gc=64, nH=4, dh=32, Hk=Wk=16, n=256)
#define HW 4096
#define NCH 128

typedef __attribute__((ext_vector_type(8))) short short8;
typedef __attribute__((ext_vector_type(4))) float f32x4;

__device__ __forceinline__ short f2bf(float f) {
  union { __hip_bfloat16 h; short s; } u;
  u.h = __float2bfloat16(f);
  return u.s;
}
__device__ __forceinline__ float bf2f(short s) {
  union { unsigned u; float f; } u;
  u.u = ((unsigned)(unsigned short)s) << 16;
  return u.f;
}

// ---------------------------------------------------------------------------
// K0: weight conversions: wq -> bf16 hi/lo split; wk, wv, wo -> bf16
// ---------------------------------------------------------------------------
__global__ __launch_bounds__(256) void wcvt_kernel(
    const float* __restrict__ wq, const float* __restrict__ wk,
    const float* __restrict__ wv, const float* __restrict__ wo,
    short* __restrict__ wq_hi, short* __restrict__ wq_lo,
    short* __restrict__ wk_bf, short* __restrict__ wv_bf,
    short* __restrict__ wo_bf) {
  int i = blockIdx.x * 256 + threadIdx.x;  // 16384 total
  float q = wq[i];
  short h = f2bf(q);
  wq_hi[i] = h;
  wq_lo[i] = f2bf(q - bf2f(h));
  wk_bf[i] = f2bf(wk[i]);
  wv_bf[i] = f2bf(wv[i]);
  wo_bf[i] = f2bf(wo[i]);
}

// ---------------------------------------------------------------------------
// K1: transpose x [b][c][m] fp32 -> xT hi/lo bf16 [b][m][c]  (x = hi+lo exact
// to ~2^-17 rel).  64x64 LDS tile, conflict-free (65 pad).
// ---------------------------------------------------------------------------
__global__ __launch_bounds__(256) void xcvt_kernel(const float* __restrict__ x,
                                                   short* __restrict__ xhi,
                                                   short* __restrict__ xlo) {
  __shared__ float s[64][65];
  int b = blockIdx.z;
  int c0 = blockIdx.y * 64;
  int m0 = blockIdx.x * 64;
  int tid = threadIdx.x;
  {
    int ml = tid & 63, ch = tid >> 6;
#pragma unroll
    for (int i = 0; i < 16; ++i) {
      int cl = i * 4 + ch;
      s[cl][ml] = x[((size_t)(b * NCH + c0 + cl)) * HW + m0 + ml];
    }
  }
  __syncthreads();
  {
    int cl = tid & 63, mh = tid >> 6;
#pragma unroll
    for (int i = 0; i < 16; ++i) {
      int ml = i * 4 + mh;
      float v = s[cl][ml];
      short hi = f2bf(v);
      short lo = f2bf(v - bf2f(hi));
      size_t idx = ((size_t)(b * HW + m0 + ml)) * NCH + c0 + cl;
      xhi[idx] = hi;
      xlo[idx] = lo;
    }
  }
}

// ---------------------------------------------------------------------------
// K2: qT[b][m][o] fp32 = wq * x via MFMA bf16x3 split (whi*xhi + whi*xlo +
// wlo*xhi; dropped wlo*xlo ~ 2^-18).  Wave = 16m x 128o, block = 64m.
// ---------------------------------------------------------------------------
__global__ __launch_bounds__(256) void qmfma_kernel(
    const short* __restrict__ xhi, const short* __restrict__ xlo,
    const short* __restrict__ whi, const short* __restrict__ wlo,
    float* __restrict__ qT) {
  int tid = threadIdx.x;
  int w = tid >> 6, lane = tid & 63, l15 = lane & 15, qd = lane >> 4;
  int b = blockIdx.y;
  int m0 = blockIdx.x * 64 + w * 16;

  f32x4 acc[8];
#pragma unroll
  for (int ot = 0; ot < 8; ++ot) acc[ot] = (f32x4){0.f, 0.f, 0.f, 0.f};

  size_t arow = ((size_t)(b * HW + m0 + l15)) * NCH + qd * 8;
#pragma unroll
  for (int kc = 0; kc < 4; ++kc) {
    short8 ah = *(const short8*)&xhi[arow + kc * 32];
    short8 al = *(const short8*)&xlo[arow + kc * 32];
#pragma unroll
    for (int ot = 0; ot < 8; ++ot) {
      size_t wrow = (size_t)(ot * 16 + l15) * NCH + kc * 32 + qd * 8;
      short8 bh = *(const short8*)&whi[wrow];
      short8 bl = *(const short8*)&wlo[wrow];
      acc[ot] = __builtin_amdgcn_mfma_f32_16x16x32_bf16(ah, bh, acc[ot], 0, 0, 0);
      acc[ot] = __builtin_amdgcn_mfma_f32_16x16x32_bf16(al, bh, acc[ot], 0, 0, 0);
      acc[ot] = __builtin_amdgcn_mfma_f32_16x16x32_bf16(ah, bl, acc[ot], 0, 0, 0);
    }
  }
  // D: row = m (qd*4+r), col = o (l15)
#pragma unroll
  for (int ot = 0; ot < 8; ++ot)
#pragma unroll
    for (int r = 0; r < 4; ++r)
      qT[((size_t)(b * HW + m0 + qd * 4 + r)) * NCH + ot * 16 + l15] = acc[ot][r];
}

// ---------------------------------------------------------------------------
// K3: conv_offset: depthwise 5x5 s4 p2 -> BiasFree LN -> GELU -> 1x1(3) ->
// tanh/sigmoid -> pos + dm.  One wave per (bg, p); taps now coalesced (qT).
// ---------------------------------------------------------------------------
__device__ __forceinline__ float wsum64(float v) {
#pragma unroll
  for (int o = 32; o > 0; o >>= 1) v += __shfl_xor(v, o);
  return v;
}

__global__ __launch_bounds__(64) void conv_offset_kernel(
    const float* __restrict__ qT, const float* __restrict__ w_dw,
    const float* __restrict__ ln_w, const float* __restrict__ w_off,
    float* __restrict__ pos, float* __restrict__ dm) {
  int c = threadIdx.x;       // 0..63
  int p = blockIdx.x;        // 0..255
  int bg = blockIdx.y;       // 0..15
  int py = p >> 4, px = p & 15;
  const float* qp = qT + (size_t)(bg >> 1) * HW * NCH + (bg & 1) * 64 + c;
  const float* wd = w_dw + c * 25;
  float acc = 0.f;
#pragma unroll
  for (int ky = 0; ky < 5; ++ky) {
    int iy = 4 * py + ky - 2;
    if (iy < 0 || iy >= 64) continue;
#pragma unroll
    for (int kx = 0; kx < 5; ++kx) {
      int ix = 4 * px + kx - 2;
      if (ix < 0 || ix >= 64) continue;
      acc += wd[ky * 5 + kx] * qp[(size_t)(iy * 64 + ix) * NCH];
    }
  }
  float mean = wsum64(acc) * (1.f / 64.f);
  float msq = wsum64(acc * acc) * (1.f / 64.f);
  float var = msq - mean * mean;
  float g = acc * rsqrtf(var + 1e-5f) * ln_w[c];
  g = 0.5f * g * (1.f + erff(g * 0.70710678118654752f));
  float o0 = wsum64(w_off[c] * g);
  float o1 = wsum64(w_off[64 + c] * g);
  float o2 = wsum64(w_off[128 + c] * g);
  if (c == 0) {
    int idx = bg * 256 + p;
    pos[idx * 2] = tanhf(o0) * (1.f / 16.f) + ((py + 0.5f) * (1.f / 8.f) - 1.f);
    pos[idx * 2 + 1] = tanhf(o1) * (1.f / 16.f) + ((px + 0.5f) * (1.f / 8.f) - 1.f);
    dm[idx] = 1.f / (1.f + expf(-o2));
  }
}

// ---------------------------------------------------------------------------
// K4: xsT[b][n][c] bf16 = grid_sample(x, pos)*dm.  Lanes over c: each corner
// row read is a coalesced 128B bf16 pair (hi+lo = exact fp32 x).
// ---------------------------------------------------------------------------
__global__ __launch_bounds__(256) void sample_xs_kernel(
    const short* __restrict__ xhi, const short* __restrict__ xlo,
    const float* __restrict__ pos, const float* __restrict__ dm,
    short* __restrict__ xsT) {
  int tid = threadIdx.x;
  int c = tid & 63, w = tid >> 6;
  int bg = blockIdx.x;
  int p0 = blockIdx.y * 16 + w * 4;
  int b = bg >> 1, ch0 = (bg & 1) * 64;
  size_t rb = (size_t)b * HW * NCH + ch0 + c;
#pragma unroll
  for (int i = 0; i < 4; ++i) {
    int p = p0 + i;
    int idx = bg * 256 + p;
    float posy = pos[idx * 2], posx = pos[idx * 2 + 1];
    float dmv = dm[idx];
    float gx = (posx + 1.f) * 31.5f;
    float gy = (posy + 1.f) * 31.5f;
    float x0f = floorf(gx), y0f = floorf(gy);
    int ix = (int)x0f, iy = (int)y0f;
    float fx = gx - x0f, fy = gy - y0f;
    float w00 = (1.f - fx) * (1.f - fy), w10 = fx * (1.f - fy);
    float w01 = (1.f - fx) * fy, w11 = fx * fy;
    bool vx0 = (ix >= 0 && ix < 64), vx1 = (ix + 1 >= 0 && ix + 1 < 64);
    bool vy0 = (iy >= 0 && iy < 64), vy1 = (iy + 1 >= 0 && iy + 1 < 64);
    if (!(vx0 && vy0)) w00 = 0.f;
    if (!(vx1 && vy0)) w10 = 0.f;
    if (!(vx0 && vy1)) w01 = 0.f;
    if (!(vx1 && vy1)) w11 = 0.f;
    int x0c = min(max(ix, 0), 63), x1c = min(max(ix + 1, 0), 63);
    int y0c = min(max(iy, 0), 63), y1c = min(max(iy + 1, 0), 63);
    size_t i00 = rb + (size_t)(y0c * 64 + x0c) * NCH;
    size_t i10 = rb + (size_t)(y0c * 64 + x1c) * NCH;
    size_t i01 = rb + (size_t)(y1c * 64 + x0c) * NCH;
    size_t i11 = rb + (size_t)(y1c * 64 + x1c) * NCH;
    float v = w00 * (bf2f(xhi[i00]) + bf2f(xlo[i00])) +
              w10 * (bf2f(xhi[i10]) + bf2f(xlo[i10])) +
              w01 * (bf2f(xhi[i01]) + bf2f(xlo[i01])) +
              w11 * (bf2f(xhi[i11]) + bf2f(xlo[i11]));
    xsT[((size_t)(b * 256 + p)) * NCH + ch0 + c] = f2bf(v * dmv);
  }
}

// ---------------------------------------------------------------------------
// K5: k,v via MFMA from xsT.  kbf[bh][n][dh], vbf[bh][dh][n].
// grid (bh=32, n-half=2, which=2), 4 waves x 2 n-tiles each.
// ---------------------------------------------------------------------------
__global__ __launch_bounds__(256) void kv_mfma_kernel(
    const short* __restrict__ xsT, const short* __restrict__ wk_bf,
    const short* __restrict__ wv_bf, short* __restrict__ kbf,
    short* __restrict__ vbf) {
  int tid = threadIdx.x;
  int w = tid >> 6, lane = tid & 63, l15 = lane & 15, qd = lane >> 4;
  int bh = blockIdx.x, b = bh >> 2;
  int n0 = blockIdx.y * 128;
  f32x4 acc[2][2];
#pragma unroll
  for (int t = 0; t < 2; ++t)
#pragma unroll
    for (int ot = 0; ot < 2; ++ot) acc[t][ot] = (f32x4){0.f, 0.f, 0.f, 0.f};

  if (blockIdx.z == 0) {  // K: A = xsT rows (n), B = wk rows (o)
#pragma unroll
    for (int t = 0; t < 2; ++t) {
      int nt = w * 2 + t;
      size_t arow = ((size_t)(b * 256 + n0 + nt * 16 + l15)) * NCH + qd * 8;
#pragma unroll
      for (int kc = 0; kc < 4; ++kc) {
        short8 a = *(const short8*)&xsT[arow + kc * 32];
#pragma unroll
        for (int ot = 0; ot < 2; ++ot) {
          short8 bb = *(const short8*)&wk_bf[(size_t)(bh % 4 * 32 + ot * 16 + l15) * NCH + kc * 32 + qd * 8];
          acc[t][ot] = __builtin_amdgcn_mfma_f32_16x16x32_bf16(a, bb, acc[t][ot], 0, 0, 0);
        }
      }
    }
#pragma unroll
    for (int t = 0; t < 2; ++t)
#pragma unroll
      for (int ot = 0; ot < 2; ++ot)
#pragma unroll
        for (int r = 0; r < 4; ++r)
          kbf[((size_t)(bh * 256 + n0 + (w * 2 + t) * 16 + qd * 4 + r)) * 32 +
              ot * 16 + l15] = f2bf(acc[t][ot][r]);
  } else {  // V: A = wv rows (o), B = xsT rows (n)
#pragma unroll
    for (int t = 0; t < 2; ++t) {
      int nt = w * 2 + t;
      size_t brow = ((size_t)(b * 256 + n0 + nt * 16 + l15)) * NCH + qd * 8;
#pragma unroll
      for (int kc = 0; kc < 4; ++kc) {
        short8 bb = *(const short8*)&xsT[brow + kc * 32];
#pragma unroll
        for (int ot = 0; ot < 2; ++ot) {
          short8 a = *(const short8*)&wv_bf[(size_t)(bh % 4 * 32 + ot * 16 + l15) * NCH + kc * 32 + qd * 8];
          acc[t][ot] = __builtin_amdgcn_mfma_f32_16x16x32_bf16(a, bb, acc[t][ot], 0, 0, 0);
        }
      }
    }
#pragma unroll
    for (int t = 0; t < 2; ++t)
#pragma unroll
      for (int ot = 0; ot < 2; ++ot)
#pragma unroll
        for (int r = 0; r < 4; ++r)
          vbf[((size_t)(bh * 32 + ot * 16 + qd * 4 + r)) * 256 + n0 +
              (w * 2 + t) * 16 + l15] = f2bf(acc[t][ot][r]);
  }
}

// ---------------------------------------------------------------------------
// K6: MFMA attention with LDS-staged RPE (overlaid by P after a barrier).
// Proper zero-masking on the RPE bilinear (gy,gx in (-0.984,126.984): edges
// -1 and 126 DO occur).  qfrag from qT (two dwordx4).
// ---------------------------------------------------------------------------
#define PROW 264

__global__ __launch_bounds__(256) void attn_kernel(
    const float* __restrict__ qT, const short* __restrict__ kbf,
    const short* __restrict__ vbf, const float* __restrict__ pos,
    const float* __restrict__ rpe, short* __restrict__ outT) {
  __shared__ __align__(16) float s_buf[127 * 127];  // 64516 B

  int tid = threadIdx.x;
  int wv = tid >> 6;
  int lane = tid & 63;
  int l15 = lane & 15;
  int qd = lane >> 4;
  int bh = blockIdx.y;
  int b = bh >> 2, h = bh & 3;
  int bg = b * 2 + (h >> 1);
  int m0 = blockIdx.x * 64 + wv * 16;

  {
    const float* rp = rpe + (size_t)h * (127 * 127);
    for (int i = tid; i < 127 * 127; i += 256) s_buf[i] = rp[i];
  }

  // Q B-fragment from qT [b][m][c]: 8 consecutive floats
  short8 qfrag;
  {
    const float* qg = qT + ((size_t)(b * HW + m0 + l15)) * NCH + h * 32 + qd * 8;
    f32x4 a0 = *(const f32x4*)qg;
    f32x4 a1 = *(const f32x4*)(qg + 4);
#pragma unroll
    for (int j = 0; j < 4; ++j) {
      qfrag[j] = f2bf(a0[j]);
      qfrag[4 + j] = f2bf(a1[j]);
    }
  }

  f32x4 acc[16];
  {
    const short* kb = kbf + ((size_t)bh * 256 + l15) * 32 + qd * 8;
#pragma unroll
    for (int t = 0; t < 16; ++t) {
      short8 kf = *(const short8*)(kb + t * 16 * 32);
      acc[t] = __builtin_amdgcn_mfma_f32_16x16x32_bf16(
          kf, qfrag, (f32x4){0.f, 0.f, 0.f, 0.f}, 0, 0, 0);
    }
  }
  __syncthreads();  // rpe staged

  int m = m0 + l15;
  float gy0 = ((((float)(m >> 6) + 0.5f) * (1.f / 32.f) - 1.f) * 0.5f + 1.f) * 63.f;
  float gx0 = ((((float)(m & 63) + 0.5f) * (1.f / 32.f) - 1.f) * 0.5f + 1.f) * 63.f;
  const float* posg = pos + (size_t)bg * 512;
  float mx = -1e30f;
#pragma unroll
  for (int t = 0; t < 16; ++t) {
#pragma unroll
    for (int r = 0; r < 4; ++r) {
      int n = t * 16 + qd * 4 + r;
      float2 pp = *(const float2*)&posg[n * 2];
      float gy = gy0 - pp.x * 31.5f;
      float gx = gx0 - pp.y * 31.5f;
      float y0f = floorf(gy), x0f = floorf(gx);
      int iy = (int)y0f, ix = (int)x0f;  // iy,ix in [-1,126]
      float fy = gy - y0f, fx = gx - x0f;
      float wy0 = (iy >= 0) ? (1.f - fy) : 0.f;
      float wy1 = (iy <= 125) ? fy : 0.f;
      float wx0 = (ix >= 0) ? (1.f - fx) : 0.f;
      float wx1 = (ix <= 125) ? fx : 0.f;
      int y0c = max(iy, 0), y1c = min(iy + 1, 126);
      int x0c = max(ix, 0), x1c = min(ix + 1, 126);
      float t00 = s_buf[y0c * 127 + x0c], t10 = s_buf[y0c * 127 + x1c];
      float t01 = s_buf[y1c * 127 + x0c], t11 = s_buf[y1c * 127 + x1c];
      float bias = wy0 * (wx0 * t00 + wx1 * t10) + wy1 * (wx0 * t01 + wx1 * t11);
      float s = acc[t][r] * 0.17677669529663688f + bias;
      acc[t][r] = s;
      mx = fmaxf(mx, s);
    }
  }
  mx = fmaxf(mx, __shfl_xor(mx, 16));
  float M = fmaxf(mx, __shfl_xor(mx, 32));

  float sm = 0.f;
#pragma unroll
  for (int t = 0; t < 16; ++t) {
#pragma unroll
    for (int r = 0; r < 4; ++r) {
      float e = __expf(acc[t][r] - M);
      acc[t][r] = e;
      sm += e;
    }
  }
  sm += __shfl_xor(sm, 16);
  sm += __shfl_xor(sm, 32);
  float inv = 1.f / sm;

  __syncthreads();  // all rpe reads done before P overlays s_buf

  short* s_p = (short*)s_buf;
  {
    short* pw = s_p + wv * 16 * PROW + l15 * PROW;
#pragma unroll
    for (int t = 0; t < 16; ++t) {
      int n = t * 16 + qd * 4;
      unsigned u0 = (unsigned short)f2bf(acc[t][0] * inv) |
                    ((unsigned)(unsigned short)f2bf(acc[t][1] * inv) << 16);
      unsigned u1 = (unsigned short)f2bf(acc[t][2] * inv) |
                    ((unsigned)(unsigned short)f2bf(acc[t][3] * inv) << 16);
      *(unsigned*)(pw + n) = u0;
      *(unsigned*)(pw + n + 2) = u1;
    }
  }

  f32x4 o0 = {0.f, 0.f, 0.f, 0.f}, o1 = {0.f, 0.f, 0.f, 0.f};
  {
    const short* vb = vbf + ((size_t)bh * 32 + l15) * 256 + qd * 8;
    const short* pr = s_p + wv * 16 * PROW + l15 * PROW + qd * 8;
#pragma unroll
    for (int ch = 0; ch < 8; ++ch) {
      short8 pf = *(const short8*)(pr + ch * 32);
      short8 v0 = *(const short8*)(vb + ch * 32);
      short8 v1 = *(const short8*)(vb + 16 * 256 + ch * 32);
      o0 = __builtin_amdgcn_mfma_f32_16x16x32_bf16(v0, pf, o0, 0, 0, 0);
      o1 = __builtin_amdgcn_mfma_f32_16x16x32_bf16(v1, pf, o1, 0, 0, 0);
    }
  }
  {
    size_t row = (size_t)(b * HW + m0 + l15) * NCH + h * 32 + qd * 4;
    short4 s0, s1;
    s0.x = f2bf(o0[0]); s0.y = f2bf(o0[1]); s0.z = f2bf(o0[2]); s0.w = f2bf(o0[3]);
    s1.x = f2bf(o1[0]); s1.y = f2bf(o1[1]); s1.z = f2bf(o1[2]); s1.w = f2bf(o1[3]);
    *(short4*)&outT[row] = s0;
    *(short4*)&outT[row + 16] = s1;
  }
}

// ---------------------------------------------------------------------------
// K7: final conv via MFMA: out[b][o][m] = sum_c wo[o][c] * outT[b][m][c]
// ---------------------------------------------------------------------------
__global__ __launch_bounds__(256) void wo_mfma_kernel(
    const short* __restrict__ attnT, const short* __restrict__ wo_bf,
    float* __restrict__ out) {
  int tid = threadIdx.x;
  int wv = tid >> 6;
  int lane = tid & 63;
  int l15 = lane & 15;
  int qd = lane >> 4;
  int b = blockIdx.x >> 6;
  int m0 = (blockIdx.x & 63) * 64 + wv * 16;

  f32x4 acc[8];
#pragma unroll
  for (int ot = 0; ot < 8; ++ot) acc[ot] = (f32x4){0.f, 0.f, 0.f, 0.f};

  const short* arow = attnT + (size_t)(b * HW + m0 + l15) * NCH + qd * 8;
  const short* wrow = wo_bf + (size_t)l15 * NCH + qd * 8;
#pragma unroll
  for (int kc = 0; kc < 4; ++kc) {
    short8 afrag = *(const short8*)(arow + kc * 32);
#pragma unroll
    for (int ot = 0; ot < 8; ++ot) {
      short8 bfrag = *(const short8*)(wrow + (size_t)ot * 16 * NCH + kc * 32);
      acc[ot] = __builtin_amdgcn_mfma_f32_16x16x32_bf16(afrag, bfrag, acc[ot],
                                                        0, 0, 0);
    }
  }
#pragma unroll
  for (int ot = 0; ot < 8; ++ot) {
    float* op = out + ((size_t)b * NCH + ot * 16 + l15) * HW + m0 + qd * 4;
    *(f32x4*)op = acc[ot];
  }
}

// ---------------------------------------------------------------------------
// launch
// ---------------------------------------------------------------------------
extern "C" void kernel_launch(void* const* d_in, const int* in_sizes, int n_in,
                              void* d_out, int out_size, void* d_ws,
                              size_t ws_size, hipStream_t stream) {
  const float* x = (const float*)d_in[0];
  const float* w_dw = (const float*)d_in[1];
  const float* ln_w = (const float*)d_in[2];
  const float* w_off = (const float*)d_in[3];
  const float* wq = (const float*)d_in[4];
  const float* wk = (const float*)d_in[5];
  const float* wv = (const float*)d_in[6];
  const float* wo = (const float*)d_in[7];
  const float* rpe = (const float*)d_in[8];
  float* out = (float*)d_out;

  // qT lives in d_out (dead before wo_mfma writes out).
  // outT aliases xhi (xhi last read by sample_xs, before attn writes outT).
  float* qT = out;
  short* sb = (short*)d_ws;
  short* xhi = sb;                    // 4194304 bf16 (8.4 MB)  [alias: outT]
  short* outT = sb;
  short* xlo = sb + 4194304;          // 4194304 bf16
  short* xsT = sb + 8388608;          // 262144
  short* kbf = sb + 8650752;          // 262144
  short* vbf = sb + 8912896;          // 262144
  short* wq_hi = sb + 9175040;        // 16384
  short* wq_lo = sb + 9191424;        // 16384
  short* wk_bf = sb + 9207808;        // 16384
  short* wv_bf = sb + 9224192;        // 16384
  short* wo_bf = sb + 9240576;        // 16384
  float* pos = (float*)(sb + 9256960);  // 8192 fp32
  float* dm = pos + 8192;               // 4096 fp32
  // total ~17.8 MB

  wcvt_kernel<<<64, 256, 0, stream>>>(wq, wk, wv, wo, wq_hi, wq_lo, wk_bf,
                                      wv_bf, wo_bf);
  xcvt_kernel<<<dim3(64, 2, 8), 256, 0, stream>>>(x, xhi, xlo);
  qmfma_kernel<<<dim3(64, 8), 256, 0, stream>>>(xhi, xlo, wq_hi, wq_lo, qT);
  conv_offset_kernel<<<dim3(256, 16), 64, 0, stream>>>(qT, w_dw, ln_w, w_off,
                                                       pos, dm);
  sample_xs_kernel<<<dim3(16, 16), 256, 0, stream>>>(xhi, xlo, pos, dm, xsT);
  kv_mfma_kernel<<<dim3(32, 2, 2), 256, 0, stream>>>(xsT, wk_bf, wv_bf, kbf,
                                                     vbf);
  attn_kernel<<<dim3(64, 32), 256, 0, stream>>>(qT, kbf, vbf, pos, rpe, outT);
  wo_mfma_kernel<<<512, 256, 0, stream>>>(outT, wo_bf, out);
}

// Round 5
// 191.727 us; speedup vs baseline: 2.2903x; 1.0971x over previous
//
#include <hip/hip_runtime.h>
#include <hip/hip_bf16.h>
#include <math.h>

// Problem constants (B=8, C=128, H=W=64, G=2, gc=64, nH=4, dh=32, Hk=Wk=16, n=256)
#define HW 4096
#define NCH 128

typedef __attribute__((ext_vector_type(8))) short short8;
typedef __attribute__((ext_vector_type(4))) float f32x4;

__device__ __forceinline__ short f2bf(float f) {
  union { __hip_bfloat16 h; short s; } u;
  u.h = __float2bfloat16(f);
  return u.s;
}
__device__ __forceinline__ float bf2f(short s) {
  union { unsigned u; float f; } u;
  u.u = ((unsigned)(unsigned short)s) << 16;
  return u.f;
}

// ---------------------------------------------------------------------------
// K0a: weight conversions: wq -> bf16 hi/lo split; wk, wv, wo -> bf16
// ---------------------------------------------------------------------------
__global__ __launch_bounds__(256) void wcvt_kernel(
    const float* __restrict__ wq, const float* __restrict__ wk,
    const float* __restrict__ wv, const float* __restrict__ wo,
    short* __restrict__ wq_hi, short* __restrict__ wq_lo,
    short* __restrict__ wk_bf, short* __restrict__ wv_bf,
    short* __restrict__ wo_bf) {
  int i = blockIdx.x * 256 + threadIdx.x;  // 16384 total
  float q = wq[i];
  short h = f2bf(q);
  wq_hi[i] = h;
  wq_lo[i] = f2bf(q - bf2f(h));
  wk_bf[i] = f2bf(wk[i]);
  wv_bf[i] = f2bf(wv[i]);
  wo_bf[i] = f2bf(wo[i]);
}

// ---------------------------------------------------------------------------
// K0b: padded f16 RPE table: rpe16[h][129][130], zero border.  Reading the
// pad reproduces zeros-padding grid_sample exactly (corner weight * 0).
// Row stride 130, head stride 16800 (16B-divisible for dwordx4 staging).
// ---------------------------------------------------------------------------
__global__ __launch_bounds__(256) void rpe_pad_kernel(
    const float* __restrict__ rpe, _Float16* __restrict__ rpe16) {
  int i = blockIdx.x * 256 + threadIdx.x;
  if (i >= 4 * 16800) return;
  int h = i / 16800, r = i % 16800;
  int y = r / 130, x = r % 130;
  float v = 0.f;
  if (y >= 1 && y <= 127 && x >= 1 && x <= 127)
    v = rpe[(size_t)h * (127 * 127) + (y - 1) * 127 + (x - 1)];
  rpe16[i] = (_Float16)v;
}

// ---------------------------------------------------------------------------
// K1: transpose x [b][c][m] fp32 -> xT hi/lo bf16 [b][m][c]
// ---------------------------------------------------------------------------
__global__ __launch_bounds__(256) void xcvt_kernel(const float* __restrict__ x,
                                                   short* __restrict__ xhi,
                                                   short* __restrict__ xlo) {
  __shared__ float s[64][65];
  int b = blockIdx.z;
  int c0 = blockIdx.y * 64;
  int m0 = blockIdx.x * 64;
  int tid = threadIdx.x;
  {
    int ml = tid & 63, ch = tid >> 6;
#pragma unroll
    for (int i = 0; i < 16; ++i) {
      int cl = i * 4 + ch;
      s[cl][ml] = x[((size_t)(b * NCH + c0 + cl)) * HW + m0 + ml];
    }
  }
  __syncthreads();
  {
    int cl = tid & 63, mh = tid >> 6;
#pragma unroll
    for (int i = 0; i < 16; ++i) {
      int ml = i * 4 + mh;
      float v = s[cl][ml];
      short hi = f2bf(v);
      short lo = f2bf(v - bf2f(hi));
      size_t idx = ((size_t)(b * HW + m0 + ml)) * NCH + c0 + cl;
      xhi[idx] = hi;
      xlo[idx] = lo;
    }
  }
}

// ---------------------------------------------------------------------------
// K2: qT[b][m][o] fp32 = wq * x via MFMA bf16x3 split
// ---------------------------------------------------------------------------
__global__ __launch_bounds__(256) void qmfma_kernel(
    const short* __restrict__ xhi, const short* __restrict__ xlo,
    const short* __restrict__ whi, const short* __restrict__ wlo,
    float* __restrict__ qT) {
  int tid = threadIdx.x;
  int w = tid >> 6, lane = tid & 63, l15 = lane & 15, qd = lane >> 4;
  int b = blockIdx.y;
  int m0 = blockIdx.x * 64 + w * 16;

  f32x4 acc[8];
#pragma unroll
  for (int ot = 0; ot < 8; ++ot) acc[ot] = (f32x4){0.f, 0.f, 0.f, 0.f};

  size_t arow = ((size_t)(b * HW + m0 + l15)) * NCH + qd * 8;
#pragma unroll
  for (int kc = 0; kc < 4; ++kc) {
    short8 ah = *(const short8*)&xhi[arow + kc * 32];
    short8 al = *(const short8*)&xlo[arow + kc * 32];
#pragma unroll
    for (int ot = 0; ot < 8; ++ot) {
      size_t wrow = (size_t)(ot * 16 + l15) * NCH + kc * 32 + qd * 8;
      short8 bh = *(const short8*)&whi[wrow];
      short8 bl = *(const short8*)&wlo[wrow];
      acc[ot] = __builtin_amdgcn_mfma_f32_16x16x32_bf16(ah, bh, acc[ot], 0, 0, 0);
      acc[ot] = __builtin_amdgcn_mfma_f32_16x16x32_bf16(al, bh, acc[ot], 0, 0, 0);
      acc[ot] = __builtin_amdgcn_mfma_f32_16x16x32_bf16(ah, bl, acc[ot], 0, 0, 0);
    }
  }
#pragma unroll
  for (int ot = 0; ot < 8; ++ot)
#pragma unroll
    for (int r = 0; r < 4; ++r)
      qT[((size_t)(b * HW + m0 + qd * 4 + r)) * NCH + ot * 16 + l15] = acc[ot][r];
}

// ---------------------------------------------------------------------------
// K3: conv_offset (depthwise 5x5 s4 p2 -> LN -> GELU -> 1x1(3) -> pos/dm)
// ---------------------------------------------------------------------------
__device__ __forceinline__ float wsum64(float v) {
#pragma unroll
  for (int o = 32; o > 0; o >>= 1) v += __shfl_xor(v, o);
  return v;
}

__global__ __launch_bounds__(64) void conv_offset_kernel(
    const float* __restrict__ qT, const float* __restrict__ w_dw,
    const float* __restrict__ ln_w, const float* __restrict__ w_off,
    float* __restrict__ pos, float* __restrict__ dm) {
  int c = threadIdx.x;
  int p = blockIdx.x;
  int bg = blockIdx.y;
  int py = p >> 4, px = p & 15;
  const float* qp = qT + (size_t)(bg >> 1) * HW * NCH + (bg & 1) * 64 + c;
  const float* wd = w_dw + c * 25;
  float acc = 0.f;
#pragma unroll
  for (int ky = 0; ky < 5; ++ky) {
    int iy = 4 * py + ky - 2;
    if (iy < 0 || iy >= 64) continue;
#pragma unroll
    for (int kx = 0; kx < 5; ++kx) {
      int ix = 4 * px + kx - 2;
      if (ix < 0 || ix >= 64) continue;
      acc += wd[ky * 5 + kx] * qp[(size_t)(iy * 64 + ix) * NCH];
    }
  }
  float mean = wsum64(acc) * (1.f / 64.f);
  float msq = wsum64(acc * acc) * (1.f / 64.f);
  float var = msq - mean * mean;
  float g = acc * rsqrtf(var + 1e-5f) * ln_w[c];
  g = 0.5f * g * (1.f + erff(g * 0.70710678118654752f));
  float o0 = wsum64(w_off[c] * g);
  float o1 = wsum64(w_off[64 + c] * g);
  float o2 = wsum64(w_off[128 + c] * g);
  if (c == 0) {
    int idx = bg * 256 + p;
    pos[idx * 2] = tanhf(o0) * (1.f / 16.f) + ((py + 0.5f) * (1.f / 8.f) - 1.f);
    pos[idx * 2 + 1] = tanhf(o1) * (1.f / 16.f) + ((px + 0.5f) * (1.f / 8.f) - 1.f);
    dm[idx] = 1.f / (1.f + expf(-o2));
  }
}

// ---------------------------------------------------------------------------
// K4: xsT[b][n][c] bf16 = grid_sample(x, pos)*dm (lanes over c, coalesced)
// ---------------------------------------------------------------------------
__global__ __launch_bounds__(256) void sample_xs_kernel(
    const short* __restrict__ xhi, const short* __restrict__ xlo,
    const float* __restrict__ pos, const float* __restrict__ dm,
    short* __restrict__ xsT) {
  int tid = threadIdx.x;
  int c = tid & 63, w = tid >> 6;
  int bg = blockIdx.x;
  int p0 = blockIdx.y * 16 + w * 4;
  int b = bg >> 1, ch0 = (bg & 1) * 64;
  size_t rb = (size_t)b * HW * NCH + ch0 + c;
#pragma unroll
  for (int i = 0; i < 4; ++i) {
    int p = p0 + i;
    int idx = bg * 256 + p;
    float posy = pos[idx * 2], posx = pos[idx * 2 + 1];
    float dmv = dm[idx];
    float gx = (posx + 1.f) * 31.5f;
    float gy = (posy + 1.f) * 31.5f;
    float x0f = floorf(gx), y0f = floorf(gy);
    int ix = (int)x0f, iy = (int)y0f;
    float fx = gx - x0f, fy = gy - y0f;
    float w00 = (1.f - fx) * (1.f - fy), w10 = fx * (1.f - fy);
    float w01 = (1.f - fx) * fy, w11 = fx * fy;
    bool vx0 = (ix >= 0 && ix < 64), vx1 = (ix + 1 >= 0 && ix + 1 < 64);
    bool vy0 = (iy >= 0 && iy < 64), vy1 = (iy + 1 >= 0 && iy + 1 < 64);
    if (!(vx0 && vy0)) w00 = 0.f;
    if (!(vx1 && vy0)) w10 = 0.f;
    if (!(vx0 && vy1)) w01 = 0.f;
    if (!(vx1 && vy1)) w11 = 0.f;
    int x0c = min(max(ix, 0), 63), x1c = min(max(ix + 1, 0), 63);
    int y0c = min(max(iy, 0), 63), y1c = min(max(iy + 1, 0), 63);
    size_t i00 = rb + (size_t)(y0c * 64 + x0c) * NCH;
    size_t i10 = rb + (size_t)(y0c * 64 + x1c) * NCH;
    size_t i01 = rb + (size_t)(y1c * 64 + x0c) * NCH;
    size_t i11 = rb + (size_t)(y1c * 64 + x1c) * NCH;
    float v = w00 * (bf2f(xhi[i00]) + bf2f(xlo[i00])) +
              w10 * (bf2f(xhi[i10]) + bf2f(xlo[i10])) +
              w01 * (bf2f(xhi[i01]) + bf2f(xlo[i01])) +
              w11 * (bf2f(xhi[i11]) + bf2f(xlo[i11]));
    xsT[((size_t)(b * 256 + p)) * NCH + ch0 + c] = f2bf(v * dmv);
  }
}

// ---------------------------------------------------------------------------
// K5: k,v via MFMA from xsT.  kbf[bh][n][dh], vbf[bh][dh][n].
// ---------------------------------------------------------------------------
__global__ __launch_bounds__(256) void kv_mfma_kernel(
    const short* __restrict__ xsT, const short* __restrict__ wk_bf,
    const short* __restrict__ wv_bf, short* __restrict__ kbf,
    short* __restrict__ vbf) {
  int tid = threadIdx.x;
  int w = tid >> 6, lane = tid & 63, l15 = lane & 15, qd = lane >> 4;
  int bh = blockIdx.x, b = bh >> 2;
  int n0 = blockIdx.y * 128;
  f32x4 acc[2][2];
#pragma unroll
  for (int t = 0; t < 2; ++t)
#pragma unroll
    for (int ot = 0; ot < 2; ++ot) acc[t][ot] = (f32x4){0.f, 0.f, 0.f, 0.f};

  if (blockIdx.z == 0) {
#pragma unroll
    for (int t = 0; t < 2; ++t) {
      int nt = w * 2 + t;
      size_t arow = ((size_t)(b * 256 + n0 + nt * 16 + l15)) * NCH + qd * 8;
#pragma unroll
      for (int kc = 0; kc < 4; ++kc) {
        short8 a = *(const short8*)&xsT[arow + kc * 32];
#pragma unroll
        for (int ot = 0; ot < 2; ++ot) {
          short8 bb = *(const short8*)&wk_bf[(size_t)(bh % 4 * 32 + ot * 16 + l15) * NCH + kc * 32 + qd * 8];
          acc[t][ot] = __builtin_amdgcn_mfma_f32_16x16x32_bf16(a, bb, acc[t][ot], 0, 0, 0);
        }
      }
    }
#pragma unroll
    for (int t = 0; t < 2; ++t)
#pragma unroll
      for (int ot = 0; ot < 2; ++ot)
#pragma unroll
        for (int r = 0; r < 4; ++r)
          kbf[((size_t)(bh * 256 + n0 + (w * 2 + t) * 16 + qd * 4 + r)) * 32 +
              ot * 16 + l15] = f2bf(acc[t][ot][r]);
  } else {
#pragma unroll
    for (int t = 0; t < 2; ++t) {
      int nt = w * 2 + t;
      size_t brow = ((size_t)(b * 256 + n0 + nt * 16 + l15)) * NCH + qd * 8;
#pragma unroll
      for (int kc = 0; kc < 4; ++kc) {
        short8 bb = *(const short8*)&xsT[brow + kc * 32];
#pragma unroll
        for (int ot = 0; ot < 2; ++ot) {
          short8 a = *(const short8*)&wv_bf[(size_t)(bh % 4 * 32 + ot * 16 + l15) * NCH + kc * 32 + qd * 8];
          acc[t][ot] = __builtin_amdgcn_mfma_f32_16x16x32_bf16(a, bb, acc[t][ot], 0, 0, 0);
        }
      }
    }
#pragma unroll
    for (int t = 0; t < 2; ++t)
#pragma unroll
      for (int ot = 0; ot < 2; ++ot)
#pragma unroll
        for (int r = 0; r < 4; ++r)
          vbf[((size_t)(bh * 32 + ot * 16 + qd * 4 + r)) * 256 + n0 +
              (w * 2 + t) * 16 + l15] = f2bf(acc[t][ot][r]);
  }
}

// ---------------------------------------------------------------------------
// K6: MFMA attention, padded-f16 RPE in LDS (no masks, one addr + imm
// offsets), pos in LDS, P overlays the table after a barrier.
// LDS: 33552 B table + 2048 B pos = 35600 B -> 4 blocks/CU.
// ---------------------------------------------------------------------------
#define PROW 264       // bf16 elems per P row (528 B, 16B-aligned rows)
#define POS_OFF 33552  // byte offset of s_pos (16776 staged halves)
#define LDS_BYTES 35600

__global__ __launch_bounds__(256) void attn_kernel(
    const float* __restrict__ qT, const short* __restrict__ kbf,
    const short* __restrict__ vbf, const float* __restrict__ pos,
    const _Float16* __restrict__ rpe16, short* __restrict__ outT) {
  __shared__ __align__(16) unsigned char s_raw[LDS_BYTES];
  _Float16* tab = (_Float16*)s_raw;
  float* s_pos = (float*)(s_raw + POS_OFF);
  short* s_p = (short*)s_raw;  // P overlays the table after barrier 2

  int tid = threadIdx.x;
  int wv = tid >> 6;
  int lane = tid & 63;
  int l15 = lane & 15;
  int qd = lane >> 4;
  int bh = blockIdx.y;
  int b = bh >> 2, h = bh & 3;
  int bg = b * 2 + (h >> 1);
  int m0 = blockIdx.x * 64 + wv * 16;

  // stage padded f16 rpe (16776 halves = 2097 dwordx4) + pos (512 f)
  {
    const uint4* src = (const uint4*)(rpe16 + (size_t)h * 16800);
    uint4* dst = (uint4*)s_raw;
    for (int i = tid; i < 2097; i += 256) dst[i] = src[i];
    const float* posg = pos + (size_t)bg * 512;
    s_pos[tid] = posg[tid];
    s_pos[256 + tid] = posg[256 + tid];
  }

  // Q B-fragment from qT [b][m][c]
  short8 qfrag;
  {
    const float* qg = qT + ((size_t)(b * HW + m0 + l15)) * NCH + h * 32 + qd * 8;
    f32x4 a0 = *(const f32x4*)qg;
    f32x4 a1 = *(const f32x4*)(qg + 4);
#pragma unroll
    for (int j = 0; j < 4; ++j) {
      qfrag[j] = f2bf(a0[j]);
      qfrag[4 + j] = f2bf(a1[j]);
    }
  }

  // S^T tiles: A = K[16n x 32dh]
  f32x4 acc[16];
  {
    const short* kb = kbf + ((size_t)bh * 256 + l15) * 32 + qd * 8;
#pragma unroll
    for (int t = 0; t < 16; ++t) {
      short8 kf = *(const short8*)(kb + t * 16 * 32);
      acc[t] = __builtin_amdgcn_mfma_f32_16x16x32_bf16(
          kf, qfrag, (f32x4){0.f, 0.f, 0.f, 0.f}, 0, 0, 0);
    }
  }
  __syncthreads();  // staging done

  // scale + RPE bias + max.  base = (iy+1)*130 + (ix+1), always in-bounds.
  int m = m0 + l15;
  float gy0 = ((((float)(m >> 6) + 0.5f) * (1.f / 32.f) - 1.f) * 0.5f + 1.f) * 63.f;
  float gx0 = ((((float)(m & 63) + 0.5f) * (1.f / 32.f) - 1.f) * 0.5f + 1.f) * 63.f;
  float mx = -1e30f;
#pragma unroll
  for (int t = 0; t < 16; ++t) {
#pragma unroll
    for (int r = 0; r < 4; ++r) {
      int n = t * 16 + qd * 4 + r;
      float2 pp = *(const float2*)&s_pos[n * 2];
      float gy = gy0 - pp.x * 31.5f;
      float gx = gx0 - pp.y * 31.5f;
      float y0f = floorf(gy), x0f = floorf(gx);
      float fy = gy - y0f, fx = gx - x0f;
      int base = (int)y0f * 130 + (int)x0f + 131;
      float t00 = (float)tab[base], t10 = (float)tab[base + 1];
      float t01 = (float)tab[base + 130], t11 = (float)tab[base + 131];
      float r0 = t00 + fx * (t10 - t00);
      float r1 = t01 + fx * (t11 - t01);
      float bias = r0 + fy * (r1 - r0);
      float s = acc[t][r] * 0.17677669529663688f + bias;
      acc[t][r] = s;
      mx = fmaxf(mx, s);
    }
  }
  mx = fmaxf(mx, __shfl_xor(mx, 16));
  float M = fmaxf(mx, __shfl_xor(mx, 32));

  float sm = 0.f;
#pragma unroll
  for (int t = 0; t < 16; ++t) {
#pragma unroll
    for (int r = 0; r < 4; ++r) {
      float e = __expf(acc[t][r] - M);
      acc[t][r] = e;
      sm += e;
    }
  }
  sm += __shfl_xor(sm, 16);
  sm += __shfl_xor(sm, 32);
  float inv = 1.f / sm;

  __syncthreads();  // all table/pos reads done before P overlays

  // write normalized P (bf16) rows [m][n], one b64 per tile
  {
    short* pw = s_p + wv * 16 * PROW + l15 * PROW;
#pragma unroll
    for (int t = 0; t < 16; ++t) {
      int n = t * 16 + qd * 4;
      short4 pk;
      pk.x = f2bf(acc[t][0] * inv);
      pk.y = f2bf(acc[t][1] * inv);
      pk.z = f2bf(acc[t][2] * inv);
      pk.w = f2bf(acc[t][3] * inv);
      *(short4*)(pw + n) = pk;
    }
  }
  // no barrier: each wave reads only its own P region

  // PV: Out[c,m] = sum_n V[c,n] P[n,m]
  f32x4 o0 = {0.f, 0.f, 0.f, 0.f}, o1 = {0.f, 0.f, 0.f, 0.f};
  {
    const short* vb = vbf + ((size_t)bh * 32 + l15) * 256 + qd * 8;
    const short* pr = s_p + wv * 16 * PROW + l15 * PROW + qd * 8;
#pragma unroll
    for (int ch = 0; ch < 8; ++ch) {
      short8 pf = *(const short8*)(pr + ch * 32);
      short8 v0 = *(const short8*)(vb + ch * 32);
      short8 v1 = *(const short8*)(vb + 16 * 256 + ch * 32);
      o0 = __builtin_amdgcn_mfma_f32_16x16x32_bf16(v0, pf, o0, 0, 0, 0);
      o1 = __builtin_amdgcn_mfma_f32_16x16x32_bf16(v1, pf, o1, 0, 0, 0);
    }
  }
  {
    size_t row = (size_t)(b * HW + m0 + l15) * NCH + h * 32 + qd * 4;
    short4 s0, s1;
    s0.x = f2bf(o0[0]); s0.y = f2bf(o0[1]); s0.z = f2bf(o0[2]); s0.w = f2bf(o0[3]);
    s1.x = f2bf(o1[0]); s1.y = f2bf(o1[1]); s1.z = f2bf(o1[2]); s1.w = f2bf(o1[3]);
    *(short4*)&outT[row] = s0;
    *(short4*)&outT[row + 16] = s1;
  }
}

// ---------------------------------------------------------------------------
// K7: final conv via MFMA: out[b][o][m] = sum_c wo[o][c] * outT[b][m][c]
// ---------------------------------------------------------------------------
__global__ __launch_bounds__(256) void wo_mfma_kernel(
    const short* __restrict__ attnT, const short* __restrict__ wo_bf,
    float* __restrict__ out) {
  int tid = threadIdx.x;
  int wv = tid >> 6;
  int lane = tid & 63;
  int l15 = lane & 15;
  int qd = lane >> 4;
  int b = blockIdx.x >> 6;
  int m0 = (blockIdx.x & 63) * 64 + wv * 16;

  f32x4 acc[8];
#pragma unroll
  for (int ot = 0; ot < 8; ++ot) acc[ot] = (f32x4){0.f, 0.f, 0.f, 0.f};

  const short* arow = attnT + (size_t)(b * HW + m0 + l15) * NCH + qd * 8;
  const short* wrow = wo_bf + (size_t)l15 * NCH + qd * 8;
#pragma unroll
  for (int kc = 0; kc < 4; ++kc) {
    short8 afrag = *(const short8*)(arow + kc * 32);
#pragma unroll
    for (int ot = 0; ot < 8; ++ot) {
      short8 bfrag = *(const short8*)(wrow + (size_t)ot * 16 * NCH + kc * 32);
      acc[ot] = __builtin_amdgcn_mfma_f32_16x16x32_bf16(afrag, bfrag, acc[ot],
                                                        0, 0, 0);
    }
  }
#pragma unroll
  for (int ot = 0; ot < 8; ++ot) {
    float* op = out + ((size_t)b * NCH + ot * 16 + l15) * HW + m0 + qd * 4;
    *(f32x4*)op = acc[ot];
  }
}

// ---------------------------------------------------------------------------
// launch
// ---------------------------------------------------------------------------
extern "C" void kernel_launch(void* const* d_in, const int* in_sizes, int n_in,
                              void* d_out, int out_size, void* d_ws,
                              size_t ws_size, hipStream_t stream) {
  const float* x = (const float*)d_in[0];
  const float* w_dw = (const float*)d_in[1];
  const float* ln_w = (const float*)d_in[2];
  const float* w_off = (const float*)d_in[3];
  const float* wq = (const float*)d_in[4];
  const float* wk = (const float*)d_in[5];
  const float* wv = (const float*)d_in[6];
  const float* wo = (const float*)d_in[7];
  const float* rpe = (const float*)d_in[8];
  float* out = (float*)d_out;

  // qT lives in d_out (dead before wo_mfma writes out).
  // outT aliases xhi (xhi last read by sample_xs, before attn writes outT).
  float* qT = out;
  short* sb = (short*)d_ws;
  short* xhi = sb;                      // 4194304 bf16 (8.4 MB) [alias: outT]
  short* outT = sb;
  short* xlo = sb + 4194304;            // 4194304 bf16
  short* xsT = sb + 8388608;            // 262144
  short* kbf = sb + 8650752;            // 262144
  short* vbf = sb + 8912896;            // 262144
  short* wq_hi = sb + 9175040;          // 16384
  short* wq_lo = sb + 9191424;          // 16384
  short* wk_bf = sb + 9207808;          // 16384
  short* wv_bf = sb + 9224192;          // 16384
  short* wo_bf = sb + 9240576;          // 16384
  _Float16* rpe16 = (_Float16*)(sb + 9256960);  // 67200 f16 (16B-aligned)
  float* pos = (float*)(sb + 9324160);  // 8192 fp32
  float* dm = pos + 8192;               // 4096 fp32
  // total ~17.9 MB

  wcvt_kernel<<<64, 256, 0, stream>>>(wq, wk, wv, wo, wq_hi, wq_lo, wk_bf,
                                      wv_bf, wo_bf);
  rpe_pad_kernel<<<263, 256, 0, stream>>>(rpe, rpe16);
  xcvt_kernel<<<dim3(64, 2, 8), 256, 0, stream>>>(x, xhi, xlo);
  qmfma_kernel<<<dim3(64, 8), 256, 0, stream>>>(xhi, xlo, wq_hi, wq_lo, qT);
  conv_offset_kernel<<<dim3(256, 16), 64, 0, stream>>>(qT, w_dw, ln_w, w_off,
                                                       pos, dm);
  sample_xs_kernel<<<dim3(16, 16), 256, 0, stream>>>(xhi, xlo, pos, dm, xsT);
  kv_mfma_kernel<<<dim3(32, 2, 2), 256, 0, stream>>>(xsT, wk_bf, wv_bf, kbf,
                                                     vbf);
  attn_kernel<<<dim3(64, 32), 256, 0, stream>>>(qT, kbf, vbf, pos, rpe16,
                                                outT);
  wo_mfma_kernel<<<512, 256, 0, stream>>>(outT, wo_bf, out);
}

// Round 6
// 185.223 us; speedup vs baseline: 2.3707x; 1.0351x over previous
//
#include <hip/hip_runtime.h>
#include <hip/hip_bf16.h>
#include <math.h>

// Problem constants (B=8, C=128, H=W=64, G=2, gc=64, nH=4, dh=32, Hk=Wk=16, n=256)
#define HW 4096
#define NCH 128

typedef __attribute__((ext_vector_type(8))) short short8;
typedef __attribute__((ext_vector_type(4))) float f32x4;

__device__ __forceinline__ short f2bf(float f) {
  union { __hip_bfloat16 h; short s; } u;
  u.h = __float2bfloat16(f);
  return u.s;
}
__device__ __forceinline__ float bf2f(short s) {
  union { unsigned u; float f; } u;
  u.u = ((unsigned)(unsigned short)s) << 16;
  return u.f;
}
// unpack packed (hi<<16)|lo bf16 pair -> fp32 value hi+lo
__device__ __forceinline__ float upk(unsigned u) {
  union { unsigned u; float f; } a, b;
  a.u = u & 0xFFFF0000u;
  b.u = u << 16;
  return a.f + b.f;
}

// ---------------------------------------------------------------------------
// K0: prep: wq -> bf16 hi/lo; wk/wv/wo -> bf16; rpe -> padded f16 table
// rpe16[h][129][130] with zero border (reads of the border reproduce the
// zeros-padding grid_sample exactly).
// ---------------------------------------------------------------------------
__global__ __launch_bounds__(256) void prep_kernel(
    const float* __restrict__ wq, const float* __restrict__ wk,
    const float* __restrict__ wv, const float* __restrict__ wo,
    const float* __restrict__ rpe, short* __restrict__ wq_hi,
    short* __restrict__ wq_lo, short* __restrict__ wk_bf,
    short* __restrict__ wv_bf, short* __restrict__ wo_bf,
    _Float16* __restrict__ rpe16) {
  if (blockIdx.x < 64) {
    int i = blockIdx.x * 256 + threadIdx.x;  // 16384 weights
    float q = wq[i];
    short h = f2bf(q);
    wq_hi[i] = h;
    wq_lo[i] = f2bf(q - bf2f(h));
    wk_bf[i] = f2bf(wk[i]);
    wv_bf[i] = f2bf(wv[i]);
    wo_bf[i] = f2bf(wo[i]);
  } else {
    int i = (blockIdx.x - 64) * 256 + threadIdx.x;
    if (i >= 4 * 16800) return;
    int h = i / 16800, r = i % 16800;
    int y = r / 130, x = r % 130;
    float v = 0.f;
    if (y >= 1 && y <= 127 && x >= 1 && x <= 127)
      v = rpe[(size_t)h * (127 * 127) + (y - 1) * 127 + (x - 1)];
    rpe16[i] = (_Float16)v;
  }
}

// ---------------------------------------------------------------------------
// K1: fused transpose + q-conv.  Block = (64 m) x (128 c) tile of x:
//  phase 1: stage x tile in LDS (coalesced fp32 loads)
//  phase 2: write xpk[b][m][c] = (bf16hi<<16)|bf16lo  (exact to ~2^-17)
//  phase 3: q MFMA (bf16x3 split) from the same LDS tile -> qT[b][m][o] fp32
// ---------------------------------------------------------------------------
__global__ __launch_bounds__(256) void xq_kernel(
    const float* __restrict__ x, const short* __restrict__ whi,
    const short* __restrict__ wlo, unsigned* __restrict__ xpk,
    float* __restrict__ qT) {
  __shared__ float s[128][65];  // 33.3 KB
  int tid = threadIdx.x;
  int b = blockIdx.y;
  int m0 = blockIdx.x * 64;
  {
    int ml = tid & 63, ch = tid >> 6;
#pragma unroll
    for (int i = 0; i < 32; ++i) {
      int c = i * 4 + ch;
      s[c][ml] = x[((size_t)(b * NCH + c)) * HW + m0 + ml];
    }
  }
  __syncthreads();
  // phase 2: packed hi/lo write, coalesced along c
  {
    int c = tid & 127, mh = tid >> 7;
#pragma unroll
    for (int i = 0; i < 32; ++i) {
      int m = i * 2 + mh;
      float v = s[c][m];
      short hi = f2bf(v);
      unsigned lo = (unsigned short)f2bf(v - bf2f(hi));
      xpk[((size_t)(b * HW + m0 + m)) * NCH + c] =
          (((unsigned)(unsigned short)hi) << 16) | lo;
    }
  }
  // phase 3: q MFMA
  int w = tid >> 6, lane = tid & 63, l15 = lane & 15, qd = lane >> 4;
  int mrow = w * 16 + l15;
  f32x4 acc[8];
#pragma unroll
  for (int ot = 0; ot < 8; ++ot) acc[ot] = (f32x4){0.f, 0.f, 0.f, 0.f};
#pragma unroll
  for (int kc = 0; kc < 4; ++kc) {
    short8 ah, al;
#pragma unroll
    for (int j = 0; j < 8; ++j) {
      float v = s[kc * 32 + qd * 8 + j][mrow];
      short hi = f2bf(v);
      ah[j] = hi;
      al[j] = f2bf(v - bf2f(hi));
    }
#pragma unroll
    for (int ot = 0; ot < 8; ++ot) {
      size_t wrow = (size_t)(ot * 16 + l15) * NCH + kc * 32 + qd * 8;
      short8 bh = *(const short8*)&whi[wrow];
      short8 bl = *(const short8*)&wlo[wrow];
      acc[ot] = __builtin_amdgcn_mfma_f32_16x16x32_bf16(ah, bh, acc[ot], 0, 0, 0);
      acc[ot] = __builtin_amdgcn_mfma_f32_16x16x32_bf16(al, bh, acc[ot], 0, 0, 0);
      acc[ot] = __builtin_amdgcn_mfma_f32_16x16x32_bf16(ah, bl, acc[ot], 0, 0, 0);
    }
  }
#pragma unroll
  for (int ot = 0; ot < 8; ++ot)
#pragma unroll
    for (int r = 0; r < 4; ++r)
      qT[((size_t)(b * HW + m0 + w * 16 + qd * 4 + r)) * NCH + ot * 16 + l15] =
          acc[ot][r];
}

// ---------------------------------------------------------------------------
// K2: conv_offset (depthwise 5x5 s4 p2 -> LN -> GELU -> 1x1(3) -> pos/dm)
// 256 threads = 4 waves, one p per wave.
// ---------------------------------------------------------------------------
__device__ __forceinline__ float wsum64(float v) {
#pragma unroll
  for (int o = 32; o > 0; o >>= 1) v += __shfl_xor(v, o);
  return v;
}

__global__ __launch_bounds__(256) void conv_offset_kernel(
    const float* __restrict__ qT, const float* __restrict__ w_dw,
    const float* __restrict__ ln_w, const float* __restrict__ w_off,
    float* __restrict__ pos, float* __restrict__ dm) {
  int c = threadIdx.x & 63;
  int p = blockIdx.x * 4 + (threadIdx.x >> 6);
  int bg = blockIdx.y;
  int py = p >> 4, px = p & 15;
  const float* qp = qT + (size_t)(bg >> 1) * HW * NCH + (bg & 1) * 64 + c;
  const float* wd = w_dw + c * 25;
  float acc = 0.f;
#pragma unroll
  for (int ky = 0; ky < 5; ++ky) {
    int iy = 4 * py + ky - 2;
    if (iy < 0 || iy >= 64) continue;
#pragma unroll
    for (int kx = 0; kx < 5; ++kx) {
      int ix = 4 * px + kx - 2;
      if (ix < 0 || ix >= 64) continue;
      acc += wd[ky * 5 + kx] * qp[(size_t)(iy * 64 + ix) * NCH];
    }
  }
  float mean = wsum64(acc) * (1.f / 64.f);
  float msq = wsum64(acc * acc) * (1.f / 64.f);
  float var = msq - mean * mean;
  float g = acc * rsqrtf(var + 1e-5f) * ln_w[c];
  g = 0.5f * g * (1.f + erff(g * 0.70710678118654752f));
  float o0 = wsum64(w_off[c] * g);
  float o1 = wsum64(w_off[64 + c] * g);
  float o2 = wsum64(w_off[128 + c] * g);
  if (c == 0) {
    int idx = bg * 256 + p;
    pos[idx * 2] = tanhf(o0) * (1.f / 16.f) + ((py + 0.5f) * (1.f / 8.f) - 1.f);
    pos[idx * 2 + 1] = tanhf(o1) * (1.f / 16.f) + ((px + 0.5f) * (1.f / 8.f) - 1.f);
    dm[idx] = 1.f / (1.f + expf(-o2));
  }
}

// ---------------------------------------------------------------------------
// K3: xsT[b][n][c] bf16 = grid_sample(x, pos)*dm.  One packed-uint gather per
// corner (hi+lo reconstruct exact fp32 x).
// ---------------------------------------------------------------------------
__global__ __launch_bounds__(256) void sample_xs_kernel(
    const unsigned* __restrict__ xpk, const float* __restrict__ pos,
    const float* __restrict__ dm, short* __restrict__ xsT) {
  int tid = threadIdx.x;
  int c = tid & 63, w = tid >> 6;
  int bg = blockIdx.x;
  int p0 = blockIdx.y * 16 + w * 4;
  int b = bg >> 1, ch0 = (bg & 1) * 64;
  size_t rb = (size_t)b * HW * NCH + ch0 + c;
#pragma unroll
  for (int i = 0; i < 4; ++i) {
    int p = p0 + i;
    int idx = bg * 256 + p;
    float posy = pos[idx * 2], posx = pos[idx * 2 + 1];
    float dmv = dm[idx];
    float gx = (posx + 1.f) * 31.5f;
    float gy = (posy + 1.f) * 31.5f;
    float x0f = floorf(gx), y0f = floorf(gy);
    int ix = (int)x0f, iy = (int)y0f;
    float fx = gx - x0f, fy = gy - y0f;
    float w00 = (1.f - fx) * (1.f - fy), w10 = fx * (1.f - fy);
    float w01 = (1.f - fx) * fy, w11 = fx * fy;
    bool vx0 = (ix >= 0 && ix < 64), vx1 = (ix + 1 >= 0 && ix + 1 < 64);
    bool vy0 = (iy >= 0 && iy < 64), vy1 = (iy + 1 >= 0 && iy + 1 < 64);
    if (!(vx0 && vy0)) w00 = 0.f;
    if (!(vx1 && vy0)) w10 = 0.f;
    if (!(vx0 && vy1)) w01 = 0.f;
    if (!(vx1 && vy1)) w11 = 0.f;
    int x0c = min(max(ix, 0), 63), x1c = min(max(ix + 1, 0), 63);
    int y0c = min(max(iy, 0), 63), y1c = min(max(iy + 1, 0), 63);
    float v = w00 * upk(xpk[rb + (size_t)(y0c * 64 + x0c) * NCH]) +
              w10 * upk(xpk[rb + (size_t)(y0c * 64 + x1c) * NCH]) +
              w01 * upk(xpk[rb + (size_t)(y1c * 64 + x0c) * NCH]) +
              w11 * upk(xpk[rb + (size_t)(y1c * 64 + x1c) * NCH]);
    xsT[((size_t)(b * 256 + p)) * NCH + ch0 + c] = f2bf(v * dmv);
  }
}

// ---------------------------------------------------------------------------
// K4: k,v via MFMA from xsT.  kbf[bh][n][dh], vbf[bh][dh][n].
// ---------------------------------------------------------------------------
__global__ __launch_bounds__(256) void kv_mfma_kernel(
    const short* __restrict__ xsT, const short* __restrict__ wk_bf,
    const short* __restrict__ wv_bf, short* __restrict__ kbf,
    short* __restrict__ vbf) {
  int tid = threadIdx.x;
  int w = tid >> 6, lane = tid & 63, l15 = lane & 15, qd = lane >> 4;
  int bh = blockIdx.x, b = bh >> 2;
  int n0 = blockIdx.y * 128;
  f32x4 acc[2][2];
#pragma unroll
  for (int t = 0; t < 2; ++t)
#pragma unroll
    for (int ot = 0; ot < 2; ++ot) acc[t][ot] = (f32x4){0.f, 0.f, 0.f, 0.f};

  if (blockIdx.z == 0) {
#pragma unroll
    for (int t = 0; t < 2; ++t) {
      size_t arow = ((size_t)(b * 256 + n0 + (w * 2 + t) * 16 + l15)) * NCH + qd * 8;
#pragma unroll
      for (int kc = 0; kc < 4; ++kc) {
        short8 a = *(const short8*)&xsT[arow + kc * 32];
#pragma unroll
        for (int ot = 0; ot < 2; ++ot) {
          short8 bb = *(const short8*)&wk_bf[(size_t)((bh % 4) * 32 + ot * 16 + l15) * NCH + kc * 32 + qd * 8];
          acc[t][ot] = __builtin_amdgcn_mfma_f32_16x16x32_bf16(a, bb, acc[t][ot], 0, 0, 0);
        }
      }
    }
#pragma unroll
    for (int t = 0; t < 2; ++t)
#pragma unroll
      for (int ot = 0; ot < 2; ++ot)
#pragma unroll
        for (int r = 0; r < 4; ++r)
          kbf[((size_t)(bh * 256 + n0 + (w * 2 + t) * 16 + qd * 4 + r)) * 32 +
              ot * 16 + l15] = f2bf(acc[t][ot][r]);
  } else {
#pragma unroll
    for (int t = 0; t < 2; ++t) {
      size_t brow = ((size_t)(b * 256 + n0 + (w * 2 + t) * 16 + l15)) * NCH + qd * 8;
#pragma unroll
      for (int kc = 0; kc < 4; ++kc) {
        short8 bb = *(const short8*)&xsT[brow + kc * 32];
#pragma unroll
        for (int ot = 0; ot < 2; ++ot) {
          short8 a = *(const short8*)&wv_bf[(size_t)((bh % 4) * 32 + ot * 16 + l15) * NCH + kc * 32 + qd * 8];
          acc[t][ot] = __builtin_amdgcn_mfma_f32_16x16x32_bf16(a, bb, acc[t][ot], 0, 0, 0);
        }
      }
    }
#pragma unroll
    for (int t = 0; t < 2; ++t)
#pragma unroll
      for (int ot = 0; ot < 2; ++ot)
#pragma unroll
        for (int r = 0; r < 4; ++r)
          vbf[((size_t)(bh * 32 + ot * 16 + qd * 4 + r)) * 256 + n0 +
              (w * 2 + t) * 16 + l15] = f2bf(acc[t][ot][r]);
  }
}

// ---------------------------------------------------------------------------
// K5: MFMA attention.  Bias loop: paired f16 corner loads (memcpy -> single
// 4B LDS access where HW allows, u16 pair fallback) + pos batched as two
// b128 per 16-sample tile.  P overlays the rpe table after barrier 2.
// ---------------------------------------------------------------------------
#define PROW 264       // bf16 elems per P row (528 B, 16B-aligned rows)
#define POS_OFF 33552  // byte offset of s_pos
#define LDS_BYTES 35600

__global__ __launch_bounds__(256) void attn_kernel(
    const float* __restrict__ qT, const short* __restrict__ kbf,
    const short* __restrict__ vbf, const float* __restrict__ pos,
    const _Float16* __restrict__ rpe16, short* __restrict__ outT) {
  __shared__ __align__(16) unsigned char s_raw[LDS_BYTES];
  _Float16* tab = (_Float16*)s_raw;
  float* s_pos = (float*)(s_raw + POS_OFF);
  short* s_p = (short*)s_raw;

  int tid = threadIdx.x;
  int wv = tid >> 6;
  int lane = tid & 63;
  int l15 = lane & 15;
  int qd = lane >> 4;
  int bh = blockIdx.y;
  int b = bh >> 2, h = bh & 3;
  int bg = b * 2 + (h >> 1);
  int m0 = blockIdx.x * 64 + wv * 16;

  {
    const uint4* src = (const uint4*)(rpe16 + (size_t)h * 16800);
    uint4* dst = (uint4*)s_raw;
    for (int i = tid; i < 2097; i += 256) dst[i] = src[i];
    const float* posg = pos + (size_t)bg * 512;
    s_pos[tid] = posg[tid];
    s_pos[256 + tid] = posg[256 + tid];
  }

  short8 qfrag;
  {
    const float* qg = qT + ((size_t)(b * HW + m0 + l15)) * NCH + h * 32 + qd * 8;
    f32x4 a0 = *(const f32x4*)qg;
    f32x4 a1 = *(const f32x4*)(qg + 4);
#pragma unroll
    for (int j = 0; j < 4; ++j) {
      qfrag[j] = f2bf(a0[j]);
      qfrag[4 + j] = f2bf(a1[j]);
    }
  }

  f32x4 acc[16];
  {
    const short* kb = kbf + ((size_t)bh * 256 + l15) * 32 + qd * 8;
#pragma unroll
    for (int t = 0; t < 16; ++t) {
      short8 kf = *(const short8*)(kb + t * 16 * 32);
      acc[t] = __builtin_amdgcn_mfma_f32_16x16x32_bf16(
          kf, qfrag, (f32x4){0.f, 0.f, 0.f, 0.f}, 0, 0, 0);
    }
  }
  __syncthreads();  // staging done

  int m = m0 + l15;
  float gy0 = ((((float)(m >> 6) + 0.5f) * (1.f / 32.f) - 1.f) * 0.5f + 1.f) * 63.f;
  float gx0 = ((((float)(m & 63) + 0.5f) * (1.f / 32.f) - 1.f) * 0.5f + 1.f) * 63.f;
  float mx = -1e30f;
#pragma unroll
  for (int t = 0; t < 16; ++t) {
    const f32x4* pp4 = (const f32x4*)&s_pos[(t * 16 + qd * 4) * 2];
    f32x4 pA = pp4[0];  // p0y p0x p1y p1x
    f32x4 pB = pp4[1];  // p2y p2x p3y p3x
    float py[4] = {pA[0], pA[2], pB[0], pB[2]};
    float px[4] = {pA[1], pA[3], pB[1], pB[3]};
#pragma unroll
    for (int r = 0; r < 4; ++r) {
      float gy = gy0 - py[r] * 31.5f;
      float gx = gx0 - px[r] * 31.5f;
      float y0f = floorf(gy), x0f = floorf(gx);
      float fy = gy - y0f, fx = gx - x0f;
      int base = (int)y0f * 130 + (int)x0f + 131;
      unsigned u0, u1;
      __builtin_memcpy(&u0, (const char*)tab + 2 * base, 4);
      __builtin_memcpy(&u1, (const char*)tab + 2 * base + 260, 4);
      union { unsigned u; _Float16 h[2]; } c0, c1;
      c0.u = u0;
      c1.u = u1;
      float t00 = (float)c0.h[0], t10 = (float)c0.h[1];
      float t01 = (float)c1.h[0], t11 = (float)c1.h[1];
      float r0 = t00 + fx * (t10 - t00);
      float r1 = t01 + fx * (t11 - t01);
      float bias = r0 + fy * (r1 - r0);
      float s = fmaf(acc[t][r], 0.17677669529663688f, bias);
      acc[t][r] = s;
      mx = fmaxf(mx, s);
    }
  }
  mx = fmaxf(mx, __shfl_xor(mx, 16));
  float M = fmaxf(mx, __shfl_xor(mx, 32));

  float sm = 0.f;
#pragma unroll
  for (int t = 0; t < 16; ++t) {
#pragma unroll
    for (int r = 0; r < 4; ++r) {
      float e = __expf(acc[t][r] - M);
      acc[t][r] = e;
      sm += e;
    }
  }
  sm += __shfl_xor(sm, 16);
  sm += __shfl_xor(sm, 32);
  float inv = 1.f / sm;

  __syncthreads();  // all table/pos reads done before P overlays

  {
    short* pw = s_p + wv * 16 * PROW + l15 * PROW;
#pragma unroll
    for (int t = 0; t < 16; ++t) {
      int n = t * 16 + qd * 4;
      short4 pk;
      pk.x = f2bf(acc[t][0] * inv);
      pk.y = f2bf(acc[t][1] * inv);
      pk.z = f2bf(acc[t][2] * inv);
      pk.w = f2bf(acc[t][3] * inv);
      *(short4*)(pw + n) = pk;
    }
  }
  // no barrier: each wave reads only its own P region

  f32x4 o0 = {0.f, 0.f, 0.f, 0.f}, o1 = {0.f, 0.f, 0.f, 0.f};
  {
    const short* vb = vbf + ((size_t)bh * 32 + l15) * 256 + qd * 8;
    const short* pr = s_p + wv * 16 * PROW + l15 * PROW + qd * 8;
#pragma unroll
    for (int ch = 0; ch < 8; ++ch) {
      short8 pf = *(const short8*)(pr + ch * 32);
      short8 v0 = *(const short8*)(vb + ch * 32);
      short8 v1 = *(const short8*)(vb + 16 * 256 + ch * 32);
      o0 = __builtin_amdgcn_mfma_f32_16x16x32_bf16(v0, pf, o0, 0, 0, 0);
      o1 = __builtin_amdgcn_mfma_f32_16x16x32_bf16(v1, pf, o1, 0, 0, 0);
    }
  }
  {
    size_t row = (size_t)(b * HW + m0 + l15) * NCH + h * 32 + qd * 4;
    short4 s0, s1;
    s0.x = f2bf(o0[0]); s0.y = f2bf(o0[1]); s0.z = f2bf(o0[2]); s0.w = f2bf(o0[3]);
    s1.x = f2bf(o1[0]); s1.y = f2bf(o1[1]); s1.z = f2bf(o1[2]); s1.w = f2bf(o1[3]);
    *(short4*)&outT[row] = s0;
    *(short4*)&outT[row + 16] = s1;
  }
}

// ---------------------------------------------------------------------------
// K6: final conv via MFMA: out[b][o][m] = sum_c wo[o][c] * outT[b][m][c]
// ---------------------------------------------------------------------------
__global__ __launch_bounds__(256) void wo_mfma_kernel(
    const short* __restrict__ attnT, const short* __restrict__ wo_bf,
    float* __restrict__ out) {
  int tid = threadIdx.x;
  int wv = tid >> 6;
  int lane = tid & 63;
  int l15 = lane & 15;
  int qd = lane >> 4;
  int b = blockIdx.x >> 6;
  int m0 = (blockIdx.x & 63) * 64 + wv * 16;

  f32x4 acc[8];
#pragma unroll
  for (int ot = 0; ot < 8; ++ot) acc[ot] = (f32x4){0.f, 0.f, 0.f, 0.f};

  const short* arow = attnT + (size_t)(b * HW + m0 + l15) * NCH + qd * 8;
  const short* wrow = wo_bf + (size_t)l15 * NCH + qd * 8;
#pragma unroll
  for (int kc = 0; kc < 4; ++kc) {
    short8 afrag = *(const short8*)(arow + kc * 32);
#pragma unroll
    for (int ot = 0; ot < 8; ++ot) {
      short8 bfrag = *(const short8*)(wrow + (size_t)ot * 16 * NCH + kc * 32);
      acc[ot] = __builtin_amdgcn_mfma_f32_16x16x32_bf16(afrag, bfrag, acc[ot],
                                                        0, 0, 0);
    }
  }
#pragma unroll
  for (int ot = 0; ot < 8; ++ot) {
    float* op = out + ((size_t)b * NCH + ot * 16 + l15) * HW + m0 + qd * 4;
    *(f32x4*)op = acc[ot];
  }
}

// ---------------------------------------------------------------------------
// launch
// ---------------------------------------------------------------------------
extern "C" void kernel_launch(void* const* d_in, const int* in_sizes, int n_in,
                              void* d_out, int out_size, void* d_ws,
                              size_t ws_size, hipStream_t stream) {
  const float* x = (const float*)d_in[0];
  const float* w_dw = (const float*)d_in[1];
  const float* ln_w = (const float*)d_in[2];
  const float* w_off = (const float*)d_in[3];
  const float* wq = (const float*)d_in[4];
  const float* wk = (const float*)d_in[5];
  const float* wv = (const float*)d_in[6];
  const float* wo = (const float*)d_in[7];
  const float* rpe = (const float*)d_in[8];
  float* out = (float*)d_out;

  // qT lives in d_out (dead before wo_mfma writes out).
  // outT aliases xpk's start (xpk dead after sample_xs).
  float* qT = out;
  short* sb = (short*)d_ws;
  unsigned* xpk = (unsigned*)sb;        // 4194304 uints (16.7 MB)
  short* outT = sb;                     // 4194304 bf16 (8.4 MB), alias
  short* xsT = sb + 8388608;            // 262144
  short* kbf = sb + 8650752;            // 262144
  short* vbf = sb + 8912896;            // 262144
  short* wq_hi = sb + 9175040;          // 16384
  short* wq_lo = sb + 9191424;          // 16384
  short* wk_bf = sb + 9207808;          // 16384
  short* wv_bf = sb + 9224192;          // 16384
  short* wo_bf = sb + 9240576;          // 16384
  _Float16* rpe16 = (_Float16*)(sb + 9256960);  // 67200 f16
  float* pos = (float*)(sb + 9324160);  // 8192 fp32
  float* dm = pos + 8192;               // 4096 fp32
  // total ~17.9 MB

  prep_kernel<<<327, 256, 0, stream>>>(wq, wk, wv, wo, rpe, wq_hi, wq_lo,
                                       wk_bf, wv_bf, wo_bf, rpe16);
  xq_kernel<<<dim3(64, 8), 256, 0, stream>>>(x, wq_hi, wq_lo, xpk, qT);
  conv_offset_kernel<<<dim3(64, 16), 256, 0, stream>>>(qT, w_dw, ln_w, w_off,
                                                       pos, dm);
  sample_xs_kernel<<<dim3(16, 16), 256, 0, stream>>>(xpk, pos, dm, xsT);
  kv_mfma_kernel<<<dim3(32, 2, 2), 256, 0, stream>>>(xsT, wk_bf, wv_bf, kbf,
                                                     vbf);
  attn_kernel<<<dim3(64, 32), 256, 0, stream>>>(qT, kbf, vbf, pos, rpe16,
                                                outT);
  wo_mfma_kernel<<<512, 256, 0, stream>>>(outT, wo_bf, out);
}